// Round 4
// baseline (391.845 us; speedup 1.0000x reference)
//
#include <hip/hip_runtime.h>

#define N_NODES 20000
#define N_EDGES 600000
#define HID 128
#define NB N_NODES
#define NBLK64 313                  // ceil(20000/64)
#define BPG 40                      // CSR-build blocks per graph
#define CHUNK (N_EDGES / BPG)       // 15000
#define NPAIR (NB / 2)              // 10000

typedef unsigned int uint32;

// ---------------- workspace layout (4-byte words) ----------------
#define X1_OFF   0                  // x1 bf16-packed: 3*20000*64
#define H2_OFF   3840000            // h2 bf16-packed: 3*20000*64
#define COL_OFF  7680000            // 3*600000 int
#define RP_OFF   9480000            // 3*20001 int
#define GSUM_OFF 9540008            // 3*128 f32
#define TS_OFF   9540392            // 128 f32 sorted breakpoints
#define UV_OFF   9540520            // 129 x (U[128],V[128]) f32 = 33024
#define GH_OFF   9573544            // 3*40*10000 packed u32
#define OFFS_OFF 10773544           // 3*40*10000 packed u32 (2x u16 prefixes)
#define TOT_OFF  11973544           // 3*20000 int
// end ~ 12,033,544 words = 48.1 MB

static __device__ inline unsigned short f2bf(float f) {
    uint32 u = __float_as_uint(f);
    return (unsigned short)((u + 0x7fffu + ((u >> 16) & 1u)) >> 16);
}
static __device__ inline float bf2f(uint32 lo16) {
    return __uint_as_float(lo16 << 16);
}
static __device__ inline uint32 pack2(float a, float b) {
    return (uint32)f2bf(a) | ((uint32)f2bf(b) << 16);
}

// XCD-affinity block mapping: XCD = blockIdx & 7 (round-robin dispatch assumption).
// graphs {0,1} own 3 XCDs each, graph 2 owns 2. Returns false for idle blocks.
static __device__ inline bool xcd_map(int b, int nper, int& g, int& nb) {
    int xcd = b & 7, slot = b >> 3;
    int m, S;
    if (xcd < 3)      { g = 0; m = xcd;     S = 3; }
    else if (xcd < 6) { g = 1; m = xcd - 3; S = 3; }
    else              { g = 2; m = xcd - 6; S = 2; }
    nb = slot * S + m;
    return nb < nper;
}
#define GRID_FOR(nper) (8 * (((nper) + 1) / 2))

// ---- prep: sorted relu-breakpoints + pattern tables U/V; zero gsum ----
// x1[node] = relu(s*U[p] + V[p]),  p = #breakpoints < s
__launch_bounds__(128)
__global__ void prep_kernel(const float* __restrict__ W11, const float* __restrict__ b11,
                            const float* __restrict__ W12, const float* __restrict__ b12,
                            float* __restrict__ ts, float* __restrict__ UV,
                            float* __restrict__ gsum) {
    __shared__ float tsh[128], tss[128], wsh[128], bsh[128];
    __shared__ int order[128];
    __shared__ signed char sgn[128];
    int tid = threadIdx.x;   // 128
    float w = W11[tid], b = b11[tid];
    wsh[tid] = w; bsh[tid] = b;
    float t; int sg;
    if (w > 0.0f)      { t = -b / w; sg = 1; }
    else if (w < 0.0f) { t = -b / w; sg = -1; }
    else               { t = 3.0e38f; sg = 0; }
    tsh[tid] = t; sgn[tid] = (signed char)sg;
    __syncthreads();
    int rank = 0;
    for (int j = 0; j < 128; ++j) {
        float tj = tsh[j];
        if (tj < t || (tj == t && j < tid)) ++rank;
    }
    tss[rank] = t; order[rank] = tid;
    __syncthreads();
    ts[tid] = tss[tid];
    // thread owns output column `tid`; pattern 0 = state at s -> -inf
    float u = 0.0f, v = b12[tid];
    for (int k = 0; k < 128; ++k) {
        float wk = wsh[k];
        float w12 = W12[k * HID + tid];
        if (wk < 0.0f)                      { u += wk * w12; v += bsh[k] * w12; }
        else if (wk == 0.0f && bsh[k] > 0.0f) { v += bsh[k] * w12; }
    }
    UV[tid] = u; UV[128 + tid] = v;
    for (int p = 1; p <= 128; ++p) {
        int k = order[p - 1];
        float wk = wsh[k], bk = bsh[k];
        float w12 = W12[k * HID + tid];
        int s2 = sgn[k];
        if (s2 > 0)      { u += wk * w12; v += bk * w12; }
        else if (s2 < 0) { u -= wk * w12; v -= bk * w12; }
        UV[p * 256 + tid] = u; UV[p * 256 + 128 + tid] = v;
    }
    gsum[tid] = 0.0f; gsum[128 + tid] = 0.0f; gsum[256 + tid] = 0.0f;
}

// ---- CSR build phase A: per-block LDS histogram (packed 2x u16) ----
__launch_bounds__(256)
__global__ void hist_kernel(const int* __restrict__ ea, const int* __restrict__ ep,
                            const int* __restrict__ en, uint32* __restrict__ gh) {
    __shared__ uint32 h[NPAIR];     // 40 KB
    int g = blockIdx.y, blk = blockIdx.x, tid = threadIdx.x;
    const int* e = (g == 0) ? ea : (g == 1) ? ep : en;
    for (int i = tid; i < NPAIR; i += 256) h[i] = 0;
    __syncthreads();
    int base = blk * CHUNK;
    for (int i = tid; i < CHUNK; i += 256) {
        int dst = e[N_EDGES + base + i];
        atomicAdd(&h[dst >> 1], 1u << ((dst & 1) * 16));
    }
    __syncthreads();
    uint32* out = gh + ((size_t)g * BPG + blk) * NPAIR;
    for (int i = tid; i < NPAIR; i += 256) out[i] = h[i];
}

// ---- phase B1: per-(block,bin) prefix (u16 pair packed) + per-bin totals ----
__launch_bounds__(256)
__global__ void colscan_kernel(const uint32* __restrict__ gh, uint32* __restrict__ offsP,
                               int* __restrict__ tot) {
    int g = blockIdx.y;
    int p = blockIdx.x * 256 + threadIdx.x;
    if (p >= NPAIR) return;
    const uint32* ghg = gh + (size_t)g * BPG * NPAIR;
    uint32* og = offsP + (size_t)g * BPG * NPAIR;
    uint32 runLo = 0, runHi = 0;
    for (int k = 0; k < BPG; ++k) {
        uint32 w = ghg[(size_t)k * NPAIR + p];
        og[(size_t)k * NPAIR + p] = runLo | (runHi << 16);   // prefixes < 2^16
        runLo += w & 0xffffu;
        runHi += w >> 16;
    }
    tot[g * NB + 2 * p]     = (int)runLo;
    tot[g * NB + 2 * p + 1] = (int)runHi;
}

// ---- phase B2: exclusive scan of totals -> row_ptr ----
__global__ void scan_kernel(const int* __restrict__ tot, int* __restrict__ rp) {
    int g = blockIdx.x;
    int tid = threadIdx.x;                 // 256
    const int CH = (NB + 255) / 256;       // 79
    __shared__ int partial[256];
    int begin = tid * CH; if (begin > NB) begin = NB;
    int end = begin + CH; if (end > NB) end = NB;
    int s = 0;
    for (int i = begin; i < end; ++i) s += tot[g * NB + i];
    partial[tid] = s;
    __syncthreads();
    if (tid == 0) {
        int run = 0;
        for (int i = 0; i < 256; ++i) { int t = partial[i]; partial[i] = run; run += t; }
    }
    __syncthreads();
    int run = partial[tid];
    for (int i = begin; i < end; ++i) {
        rp[g * (NB + 1) + i] = run;
        run += tot[g * NB + i];
    }
    if (tid == 255) rp[g * (NB + 1) + NB] = run;
}

// ---- phase C: fill col[] via LDS rank counters; XCD-affinity grid ----
__launch_bounds__(256)
__global__ void fill_kernel(const int* __restrict__ ea, const int* __restrict__ ep,
                            const int* __restrict__ en, const int* __restrict__ rp,
                            const uint32* __restrict__ offsP, int* __restrict__ col) {
    __shared__ uint32 h[NPAIR];
    int g, blk;
    if (!xcd_map(blockIdx.x, BPG, g, blk)) return;
    int tid = threadIdx.x;
    const int* e = (g == 0) ? ea : (g == 1) ? ep : en;
    for (int i = tid; i < NPAIR; i += 256) h[i] = 0;
    __syncthreads();
    int base = blk * CHUNK;
    const int* rpg = rp + g * (NB + 1);
    const uint32* og = offsP + ((size_t)g * BPG + blk) * NPAIR;
    int* colg = col + (size_t)g * N_EDGES;
    for (int i = tid; i < CHUNK; i += 256) {
        int src = e[base + i];
        int dst = e[N_EDGES + base + i];
        uint32 old = atomicAdd(&h[dst >> 1], 1u << ((dst & 1) * 16));
        int rank = (int)((old >> ((dst & 1) * 16)) & 0xffffu);
        int offs = (int)((og[dst >> 1] >> ((dst & 1) * 16)) & 0xffffu);
        colg[rpg[dst] + offs + rank] = src;
    }
}

// ---- L1: scalar gather + pattern-table MLP1 -> x1 (bf16). wave per node ----
__launch_bounds__(256)
__global__ void l1_kernel(const float* __restrict__ xa, const float* __restrict__ xp,
                          const float* __restrict__ xn,
                          const int* __restrict__ rp, const int* __restrict__ col,
                          const float* __restrict__ ts, const float* __restrict__ UV,
                          uint32* __restrict__ X1) {
    __shared__ float tsh[128];
    int tid = threadIdx.x;
    if (tid < 128) tsh[tid] = ts[tid];
    __syncthreads();
    int g = blockIdx.y;
    const float* x = (g == 0) ? xa : (g == 1) ? xp : xn;
    int node = blockIdx.x * 4 + (tid >> 6);
    int lane = tid & 63;
    const int* rpg = rp + g * (NB + 1);
    const int* clg = col + (size_t)g * N_EDGES;
    int beg = rpg[node], end = rpg[node + 1];
    float s = 0.0f;
    for (int j = beg + lane; j < end; j += 64) s += x[clg[j]];
#pragma unroll
    for (int off = 32; off > 0; off >>= 1) s += __shfl_down(s, off);
    s = __shfl(s, 0);
    s += x[node];
    int lo = 0, hi = 128;
    while (lo < hi) { int mid = (lo + hi) >> 1; if (tsh[mid] < s) lo = mid + 1; else hi = mid; }
    const float* Up = UV + (size_t)lo * 256;
    float2 u = *(const float2*)&Up[lane * 2];
    float2 v = *(const float2*)&Up[128 + lane * 2];
    float r0 = fmaxf(fmaf(s, u.x, v.x), 0.0f);
    float r1 = fmaxf(fmaf(s, u.y, v.y), 0.0f);
    X1[(size_t)(g * NB + node) * 64 + lane] = pack2(r0, r1);
}

// ---- L2 aggregation: h2[node] = x1[node] + sum_j x1[col[j]]; XCD affinity ----
__launch_bounds__(256)
__global__ void gather2_kernel(const int* __restrict__ rp, const int* __restrict__ col,
                               const uint32* __restrict__ X1, uint32* __restrict__ H2) {
    int g, nb;
    if (!xcd_map(blockIdx.x, NB / 4, g, nb)) return;
    int node = nb * 4 + (threadIdx.x >> 6);
    int lane = threadIdx.x & 63;
    const int* rpg = rp + g * (NB + 1);
    const int* clg = col + (size_t)g * N_EDGES;
    int beg = rpg[node], end = rpg[node + 1];
    const uint32* Bg = X1 + (size_t)g * NB * 64;
    uint32 sv = Bg[(size_t)node * 64 + lane];
    float ax = bf2f(sv & 0xffffu), ay = bf2f(sv >> 16);
    float cx = 0.0f, cy = 0.0f;
    int j = beg;
    for (; j + 4 <= end; j += 4) {
        int s0 = clg[j], s1 = clg[j + 1], s2 = clg[j + 2], s3 = clg[j + 3];
        uint32 v0 = Bg[(size_t)s0 * 64 + lane];
        uint32 v1 = Bg[(size_t)s1 * 64 + lane];
        uint32 v2 = Bg[(size_t)s2 * 64 + lane];
        uint32 v3 = Bg[(size_t)s3 * 64 + lane];
        ax += bf2f(v0 & 0xffffu); ay += bf2f(v0 >> 16);
        cx += bf2f(v1 & 0xffffu); cy += bf2f(v1 >> 16);
        ax += bf2f(v2 & 0xffffu); ay += bf2f(v2 >> 16);
        cx += bf2f(v3 & 0xffffu); cy += bf2f(v3 >> 16);
    }
    for (; j < end; ++j) {
        uint32 v0 = Bg[(size_t)clg[j] * 64 + lane];
        ax += bf2f(v0 & 0xffffu); ay += bf2f(v0 >> 16);
    }
    ax += cx; ay += cy;
    H2[(size_t)(g * NB + node) * 64 + lane] = pack2(ax, ay);
}

// ---- fused MLP2: t = relu(h2@W21+b21) (LDS), x2 = relu(t@W22+b22), pool only ----
__launch_bounds__(512)
__global__ void mlp2_kernel(const uint32* __restrict__ H2,
                            const float* __restrict__ W21, const float* __restrict__ b21,
                            const float* __restrict__ W22, const float* __restrict__ b22,
                            float* __restrict__ gsum) {
    __shared__ float hs[64][33];       // 8.4 KB
    __shared__ float wt[32][144];      // 18.4 KB
    __shared__ uint32 tl[64][65];      // 16.6 KB, t as packed bf16
    __shared__ float psum[HID];
    int g, nb;
    if (!xcd_map(blockIdx.x, NBLK64, g, nb)) return;
    int base = nb * 64;
    int nvalid = NB - base; if (nvalid > 64) nvalid = 64;
    size_t growbase = (size_t)g * NB + base;
    int tid = threadIdx.x;             // 512
    int kg = tid & 15, ng = tid >> 4;  // 16 col-groups x 32 row-groups(2 rows)
    int k0 = kg * 8;
    int k0p = k0 + ((k0 >> 5) << 2);

    float acc[2][8];
#pragma unroll
    for (int c = 0; c < 2; ++c)
#pragma unroll
        for (int k = 0; k < 8; ++k) acc[c][k] = 0.0f;

    // ---- GEMM1: h2 @ W21 ----
    for (int t = 0; t < 4; ++t) {
        __syncthreads();
        {   // stage h2 tile: 64 rows x 32 feats (512 thr x 1 uint2)
            int n = tid >> 3, q = tid & 7;
            uint32 w0 = 0, w1 = 0;
            if (n < nvalid) {
                uint2 v = *(const uint2*)&H2[(growbase + n) * 64 + t * 16 + q * 2];
                w0 = v.x; w1 = v.y;
            }
            hs[n][q * 4 + 0] = bf2f(w0 & 0xffffu);
            hs[n][q * 4 + 1] = bf2f(w0 >> 16);
            hs[n][q * 4 + 2] = bf2f(w1 & 0xffffu);
            hs[n][q * 4 + 3] = bf2f(w1 >> 16);
        }
        {   // stage W21 tile: 32 rows x 32 float4 (512 thr x 2)
            int jj = tid >> 4, f2b = tid & 15;
#pragma unroll
            for (int c = 0; c < 2; ++c) {
                int colv = (f2b + c * 16) * 4;
                float4 v = *(const float4*)&W21[(size_t)(t * 32 + jj) * HID + colv];
                *(float4*)&wt[jj][colv + ((colv >> 5) << 2)] = v;
            }
        }
        __syncthreads();
#pragma unroll
        for (int jj = 0; jj < 32; ++jj) {
            float4 w0 = *(float4*)&wt[jj][k0p];
            float4 w1 = *(float4*)&wt[jj][k0p + 4];
#pragma unroll
            for (int c = 0; c < 2; ++c) {
                float h = hs[ng * 2 + c][jj];
                acc[c][0] += h * w0.x; acc[c][1] += h * w0.y;
                acc[c][2] += h * w0.z; acc[c][3] += h * w0.w;
                acc[c][4] += h * w1.x; acc[c][5] += h * w1.y;
                acc[c][6] += h * w1.z; acc[c][7] += h * w1.w;
            }
        }
    }
    // bias + relu -> t (bf16) in LDS
    {
        float4 bv0 = *(const float4*)&b21[k0];
        float4 bv1 = *(const float4*)&b21[k0 + 4];
#pragma unroll
        for (int c = 0; c < 2; ++c) {
            int n = ng * 2 + c;
            float r0 = fmaxf(acc[c][0] + bv0.x, 0.0f), r1 = fmaxf(acc[c][1] + bv0.y, 0.0f);
            float r2 = fmaxf(acc[c][2] + bv0.z, 0.0f), r3 = fmaxf(acc[c][3] + bv0.w, 0.0f);
            float r4 = fmaxf(acc[c][4] + bv1.x, 0.0f), r5 = fmaxf(acc[c][5] + bv1.y, 0.0f);
            float r6 = fmaxf(acc[c][6] + bv1.z, 0.0f), r7 = fmaxf(acc[c][7] + bv1.w, 0.0f);
            tl[n][(k0 >> 1) + 0] = pack2(r0, r1);
            tl[n][(k0 >> 1) + 1] = pack2(r2, r3);
            tl[n][(k0 >> 1) + 2] = pack2(r4, r5);
            tl[n][(k0 >> 1) + 3] = pack2(r6, r7);
            acc[c][0] = acc[c][1] = acc[c][2] = acc[c][3] = 0.0f;
            acc[c][4] = acc[c][5] = acc[c][6] = acc[c][7] = 0.0f;
        }
    }
    // ---- GEMM2: t @ W22 ----
    for (int t = 0; t < 4; ++t) {
        __syncthreads();   // orders tl writes (t=0) / wt reads before restage
        {
            int jj = tid >> 4, f2b = tid & 15;
#pragma unroll
            for (int c = 0; c < 2; ++c) {
                int colv = (f2b + c * 16) * 4;
                float4 v = *(const float4*)&W22[(size_t)(t * 32 + jj) * HID + colv];
                *(float4*)&wt[jj][colv + ((colv >> 5) << 2)] = v;
            }
        }
        __syncthreads();
#pragma unroll
        for (int jp = 0; jp < 16; ++jp) {
            float4 w0a = *(float4*)&wt[2 * jp][k0p];
            float4 w0b = *(float4*)&wt[2 * jp][k0p + 4];
            float4 w1a = *(float4*)&wt[2 * jp + 1][k0p];
            float4 w1b = *(float4*)&wt[2 * jp + 1][k0p + 4];
#pragma unroll
            for (int c = 0; c < 2; ++c) {
                uint32 tv = tl[ng * 2 + c][t * 16 + jp];
                float f0 = bf2f(tv & 0xffffu), f1 = bf2f(tv >> 16);
                acc[c][0] += f0 * w0a.x; acc[c][1] += f0 * w0a.y;
                acc[c][2] += f0 * w0a.z; acc[c][3] += f0 * w0a.w;
                acc[c][4] += f0 * w0b.x; acc[c][5] += f0 * w0b.y;
                acc[c][6] += f0 * w0b.z; acc[c][7] += f0 * w0b.w;
                acc[c][0] += f1 * w1a.x; acc[c][1] += f1 * w1a.y;
                acc[c][2] += f1 * w1a.z; acc[c][3] += f1 * w1a.w;
                acc[c][4] += f1 * w1b.x; acc[c][5] += f1 * w1b.y;
                acc[c][6] += f1 * w1b.z; acc[c][7] += f1 * w1b.w;
            }
        }
    }
    // ---- pool (x2 never materialized) ----
    __syncthreads();
    if (tid < HID) psum[tid] = 0.0f;
    __syncthreads();
    float4 bv0 = *(const float4*)&b22[k0];
    float4 bv1 = *(const float4*)&b22[k0 + 4];
    float ksum[8];
#pragma unroll
    for (int k = 0; k < 8; ++k) ksum[k] = 0.0f;
#pragma unroll
    for (int c = 0; c < 2; ++c) {
        int n = ng * 2 + c;
        if (n < nvalid) {
            ksum[0] += fmaxf(acc[c][0] + bv0.x, 0.0f);
            ksum[1] += fmaxf(acc[c][1] + bv0.y, 0.0f);
            ksum[2] += fmaxf(acc[c][2] + bv0.z, 0.0f);
            ksum[3] += fmaxf(acc[c][3] + bv0.w, 0.0f);
            ksum[4] += fmaxf(acc[c][4] + bv1.x, 0.0f);
            ksum[5] += fmaxf(acc[c][5] + bv1.y, 0.0f);
            ksum[6] += fmaxf(acc[c][6] + bv1.z, 0.0f);
            ksum[7] += fmaxf(acc[c][7] + bv1.w, 0.0f);
        }
    }
#pragma unroll
    for (int k = 0; k < 8; ++k) atomicAdd(&psum[k0 + k], ksum[k]);
    __syncthreads();
    if (tid < HID) atomicAdd(&gsum[g * HID + tid], psum[tid]);
}

// ---- triplet head ----
__global__ void final_kernel(const float* __restrict__ gsum, const float* __restrict__ Wf,
                             const float* __restrict__ bf, float* __restrict__ out) {
    int tid = threadIdx.x;  // 384
    int g = tid >> 7;
    int o = tid & 127;
    float acc = bf[o];
    for (int k = 0; k < HID; ++k)
        acc += gsum[g * HID + k] * Wf[k * HID + o];
    out[g * HID + o] = acc;
}

extern "C" void kernel_launch(void* const* d_in, const int* in_sizes, int n_in,
                              void* d_out, int out_size, void* d_ws, size_t ws_size,
                              hipStream_t stream) {
    const float* xa = (const float*)d_in[0];
    const int*   ea = (const int*)d_in[1];
    const float* xp = (const float*)d_in[2];
    const int*   ep = (const int*)d_in[3];
    const float* xn = (const float*)d_in[4];
    const int*   en = (const int*)d_in[5];
    const float* W11 = (const float*)d_in[6];
    const float* b11 = (const float*)d_in[7];
    const float* W12 = (const float*)d_in[8];
    const float* b12 = (const float*)d_in[9];
    const float* W21 = (const float*)d_in[10];
    const float* b21 = (const float*)d_in[11];
    const float* W22 = (const float*)d_in[12];
    const float* b22 = (const float*)d_in[13];
    const float* Wf  = (const float*)d_in[14];
    const float* bf  = (const float*)d_in[15];

    float*  ws    = (float*)d_ws;
    uint32* X1    = (uint32*)(ws + X1_OFF);
    uint32* H2    = (uint32*)(ws + H2_OFF);
    int*    col   = (int*)(ws + COL_OFF);
    int*    rp    = (int*)(ws + RP_OFF);
    float*  gsum  = ws + GSUM_OFF;
    float*  ts    = ws + TS_OFF;
    float*  UV    = ws + UV_OFF;
    uint32* gh    = (uint32*)(ws + GH_OFF);
    uint32* offsP = (uint32*)(ws + OFFS_OFF);
    int*    tot   = (int*)(ws + TOT_OFF);
    float*  out   = (float*)d_out;

    prep_kernel<<<1, 128, 0, stream>>>(W11, b11, W12, b12, ts, UV, gsum);
    hist_kernel<<<dim3(BPG, 3), 256, 0, stream>>>(ea, ep, en, gh);
    colscan_kernel<<<dim3((NPAIR + 255) / 256, 3), 256, 0, stream>>>(gh, offsP, tot);
    scan_kernel<<<3, 256, 0, stream>>>(tot, rp);
    fill_kernel<<<GRID_FOR(BPG), 256, 0, stream>>>(ea, ep, en, rp, offsP, col);
    l1_kernel<<<dim3(NB / 4, 3), 256, 0, stream>>>(xa, xp, xn, rp, col, ts, UV, X1);
    gather2_kernel<<<GRID_FOR(NB / 4), 256, 0, stream>>>(rp, col, X1, H2);
    mlp2_kernel<<<GRID_FOR(NBLK64), 512, 0, stream>>>(H2, W21, b21, W22, b22, gsum);
    final_kernel<<<1, 384, 0, stream>>>(gsum, Wf, bf, out);
}

// Round 5
// 357.183 us; speedup vs baseline: 1.0970x; 1.0970x over previous
//
#include <hip/hip_runtime.h>

#define N_NODES 20000
#define N_EDGES 600000
#define HID 128
#define NB N_NODES
#define NBLK64 313                  // ceil(20000/64)
#define BPG 40                      // CSR-build blocks per graph
#define CHUNK (N_EDGES / BPG)       // 15000
#define NPAIR (NB / 2)              // 10000

typedef unsigned int uint32;
typedef __attribute__((ext_vector_type(8))) short bf16x8v;   // 8 bf16 in 4 VGPRs
typedef __attribute__((ext_vector_type(4))) float f32x4;

// ---------------- workspace layout (4-byte words) ----------------
#define X1_OFF   0                  // x1 bf16-packed: 3*20000*64
#define H2_OFF   3840000            // h2 bf16-packed: 3*20000*64
#define COL_OFF  7680000            // 3*600000 int
#define RP_OFF   9480000            // 3*20001 int
#define GSUM_OFF 9540008            // 3*128 f32
#define TS_OFF   9540392            // 128 f32 sorted breakpoints
#define UV_OFF   9540520            // 129 x (U[128],V[128]) f32 = 33024
#define GH_OFF   9573544            // 3*40*10000 packed u32
#define OFFS_OFF 10773544           // 3*40*10000 packed u32
#define TOT_OFF  11973544           // 3*20000 int
#define W21P_OFF 12033544           // 128*128 bf16 frag-packed = 8192 words
#define W22P_OFF 12041736           // 8192 words
// end 12,049,928 words = 48.2 MB

static __device__ inline unsigned short f2bf(float f) {
    uint32 u = __float_as_uint(f);
    return (unsigned short)((u + 0x7fffu + ((u >> 16) & 1u)) >> 16);
}
static __device__ inline float bf2f(uint32 lo16) {
    return __uint_as_float(lo16 << 16);
}
static __device__ inline uint32 pack2(float a, float b) {
    return (uint32)f2bf(a) | ((uint32)f2bf(b) << 16);
}

// XCD-affinity block mapping (XCD = blockIdx & 7 round-robin heuristic).
static __device__ inline bool xcd_map(int b, int nper, int& g, int& nb) {
    int xcd = b & 7, slot = b >> 3;
    int m, S;
    if (xcd < 3)      { g = 0; m = xcd;     S = 3; }
    else if (xcd < 6) { g = 1; m = xcd - 3; S = 3; }
    else              { g = 2; m = xcd - 6; S = 2; }
    nb = slot * S + m;
    return nb < nper;
}
#define GRID_FOR(nper) (8 * (((nper) + 1) / 2))

// ---- prep: relu-breakpoint tables for L1 + bf16 frag-packed W21/W22 ----
__launch_bounds__(128)
__global__ void prep_kernel(const float* __restrict__ W11, const float* __restrict__ b11,
                            const float* __restrict__ W12, const float* __restrict__ b12,
                            const float* __restrict__ W21, const float* __restrict__ W22,
                            float* __restrict__ ts, float* __restrict__ UV,
                            uint32* __restrict__ W21p, uint32* __restrict__ W22p,
                            float* __restrict__ gsum) {
    __shared__ float tsh[128], tss[128], wsh[128], bsh[128];
    __shared__ int order[128];
    __shared__ signed char sgn[128];
    int tid = threadIdx.x;   // 128
    float w = W11[tid], b = b11[tid];
    wsh[tid] = w; bsh[tid] = b;
    float t; int sg;
    if (w > 0.0f)      { t = -b / w; sg = 1; }
    else if (w < 0.0f) { t = -b / w; sg = -1; }
    else               { t = 3.0e38f; sg = 0; }
    tsh[tid] = t; sgn[tid] = (signed char)sg;
    __syncthreads();
    int rank = 0;
    for (int j = 0; j < 128; ++j) {
        float tj = tsh[j];
        if (tj < t || (tj == t && j < tid)) ++rank;
    }
    tss[rank] = t; order[rank] = tid;
    __syncthreads();
    ts[tid] = tss[tid];
    float u = 0.0f, v = b12[tid];
    for (int k = 0; k < 128; ++k) {
        float wk = wsh[k];
        float w12 = W12[k * HID + tid];
        if (wk < 0.0f)                        { u += wk * w12; v += bsh[k] * w12; }
        else if (wk == 0.0f && bsh[k] > 0.0f) { v += bsh[k] * w12; }
    }
    UV[tid] = u; UV[128 + tid] = v;
    for (int p = 1; p <= 128; ++p) {
        int k = order[p - 1];
        float wk = wsh[k], bk = bsh[k];
        float w12 = W12[k * HID + tid];
        int s2 = sgn[k];
        if (s2 > 0)      { u += wk * w12; v += bk * w12; }
        else if (s2 < 0) { u -= wk * w12; v -= bk * w12; }
        UV[p * 256 + tid] = u; UV[p * 256 + 128 + tid] = v;
    }
    gsum[tid] = 0.0f; gsum[128 + tid] = 0.0f; gsum[256 + tid] = 0.0f;
    // frag-pack W21/W22 -> bf16. B-frag: lane l holds B[t*32+(l>>4)*8+j][c*16+(l&15)]
    for (int idx = tid; idx < 2048; idx += 128) {   // idx over (t,c,l)
        int tt = idx >> 9, c = (idx >> 6) & 7, l = idx & 63;
        int kbase = tt * 32 + (l >> 4) * 8;
        int colv = c * 16 + (l & 15);
#pragma unroll
        for (int jw = 0; jw < 4; ++jw) {
            float f0 = W21[(kbase + 2 * jw) * HID + colv];
            float f1 = W21[(kbase + 2 * jw + 1) * HID + colv];
            W21p[idx * 4 + jw] = pack2(f0, f1);
            f0 = W22[(kbase + 2 * jw) * HID + colv];
            f1 = W22[(kbase + 2 * jw + 1) * HID + colv];
            W22p[idx * 4 + jw] = pack2(f0, f1);
        }
    }
}

// ---- CSR build phase A: per-block LDS histogram (packed 2x u16) ----
__launch_bounds__(256)
__global__ void hist_kernel(const int* __restrict__ ea, const int* __restrict__ ep,
                            const int* __restrict__ en, uint32* __restrict__ gh) {
    __shared__ uint32 h[NPAIR];     // 40 KB
    int g = blockIdx.y, blk = blockIdx.x, tid = threadIdx.x;
    const int* e = (g == 0) ? ea : (g == 1) ? ep : en;
    for (int i = tid; i < NPAIR; i += 256) h[i] = 0;
    __syncthreads();
    int base = blk * CHUNK;
    for (int i = tid; i < CHUNK; i += 256) {
        int dst = e[N_EDGES + base + i];
        atomicAdd(&h[dst >> 1], 1u << ((dst & 1) * 16));
    }
    __syncthreads();
    uint32* out = gh + ((size_t)g * BPG + blk) * NPAIR;
    for (int i = tid; i < NPAIR; i += 256) out[i] = h[i];
}

// ---- phase B1: per-(block,bin) prefix (u16 pair packed) + per-bin totals ----
__launch_bounds__(256)
__global__ void colscan_kernel(const uint32* __restrict__ gh, uint32* __restrict__ offsP,
                               int* __restrict__ tot) {
    int g = blockIdx.y;
    int p = blockIdx.x * 256 + threadIdx.x;
    if (p >= NPAIR) return;
    const uint32* ghg = gh + (size_t)g * BPG * NPAIR;
    uint32* og = offsP + (size_t)g * BPG * NPAIR;
    uint32 runLo = 0, runHi = 0;
    for (int k = 0; k < BPG; ++k) {
        uint32 w = ghg[(size_t)k * NPAIR + p];
        og[(size_t)k * NPAIR + p] = runLo | (runHi << 16);
        runLo += w & 0xffffu;
        runHi += w >> 16;
    }
    tot[g * NB + 2 * p]     = (int)runLo;
    tot[g * NB + 2 * p + 1] = (int)runHi;
}

// ---- phase B2: exclusive scan of totals -> row_ptr ----
__global__ void scan_kernel(const int* __restrict__ tot, int* __restrict__ rp) {
    int g = blockIdx.x;
    int tid = threadIdx.x;                 // 256
    const int CH = (NB + 255) / 256;       // 79
    __shared__ int partial[256];
    int begin = tid * CH; if (begin > NB) begin = NB;
    int end = begin + CH; if (end > NB) end = NB;
    int s = 0;
    for (int i = begin; i < end; ++i) s += tot[g * NB + i];
    partial[tid] = s;
    __syncthreads();
    if (tid == 0) {
        int run = 0;
        for (int i = 0; i < 256; ++i) { int t = partial[i]; partial[i] = run; run += t; }
    }
    __syncthreads();
    int run = partial[tid];
    for (int i = begin; i < end; ++i) {
        rp[g * (NB + 1) + i] = run;
        run += tot[g * NB + i];
    }
    if (tid == 255) rp[g * (NB + 1) + NB] = run;
}

// ---- phase C: fill col[] via LDS rank counters; XCD-affinity grid ----
__launch_bounds__(256)
__global__ void fill_kernel(const int* __restrict__ ea, const int* __restrict__ ep,
                            const int* __restrict__ en, const int* __restrict__ rp,
                            const uint32* __restrict__ offsP, int* __restrict__ col) {
    __shared__ uint32 h[NPAIR];
    int g, blk;
    if (!xcd_map(blockIdx.x, BPG, g, blk)) return;
    int tid = threadIdx.x;
    const int* e = (g == 0) ? ea : (g == 1) ? ep : en;
    for (int i = tid; i < NPAIR; i += 256) h[i] = 0;
    __syncthreads();
    int base = blk * CHUNK;
    const int* rpg = rp + g * (NB + 1);
    const uint32* og = offsP + ((size_t)g * BPG + blk) * NPAIR;
    int* colg = col + (size_t)g * N_EDGES;
    for (int i = tid; i < CHUNK; i += 256) {
        int src = e[base + i];
        int dst = e[N_EDGES + base + i];
        uint32 old = atomicAdd(&h[dst >> 1], 1u << ((dst & 1) * 16));
        int rank = (int)((old >> ((dst & 1) * 16)) & 0xffffu);
        int offs = (int)((og[dst >> 1] >> ((dst & 1) * 16)) & 0xffffu);
        colg[rpg[dst] + offs + rank] = src;
    }
}

// ---- L1: scalar gather + pattern-table MLP1 -> x1 (bf16). wave per node ----
__launch_bounds__(256)
__global__ void l1_kernel(const float* __restrict__ xa, const float* __restrict__ xp,
                          const float* __restrict__ xn,
                          const int* __restrict__ rp, const int* __restrict__ col,
                          const float* __restrict__ ts, const float* __restrict__ UV,
                          uint32* __restrict__ X1) {
    __shared__ float tsh[128];
    int tid = threadIdx.x;
    if (tid < 128) tsh[tid] = ts[tid];
    __syncthreads();
    int g = blockIdx.y;
    const float* x = (g == 0) ? xa : (g == 1) ? xp : xn;
    int node = blockIdx.x * 4 + (tid >> 6);
    int lane = tid & 63;
    const int* rpg = rp + g * (NB + 1);
    const int* clg = col + (size_t)g * N_EDGES;
    int beg = rpg[node], end = rpg[node + 1];
    float s = 0.0f;
    for (int j = beg + lane; j < end; j += 64) s += x[clg[j]];
#pragma unroll
    for (int off = 32; off > 0; off >>= 1) s += __shfl_down(s, off);
    s = __shfl(s, 0);
    s += x[node];
    int lo = 0, hi = 128;
    while (lo < hi) { int mid = (lo + hi) >> 1; if (tsh[mid] < s) lo = mid + 1; else hi = mid; }
    const float* Up = UV + (size_t)lo * 256;
    float2 u = *(const float2*)&Up[lane * 2];
    float2 v = *(const float2*)&Up[128 + lane * 2];
    float r0 = fmaxf(fmaf(s, u.x, v.x), 0.0f);
    float r1 = fmaxf(fmaf(s, u.y, v.y), 0.0f);
    X1[(size_t)(g * NB + node) * 64 + lane] = pack2(r0, r1);
}

// ---- L2 aggregation, half-row pass (128B) so per-XCD set is L2-resident ----
// h2[node][half] = x1[node][half] + sum_j x1[col[j]][half]
__launch_bounds__(256)
__global__ void gather2_kernel(const int* __restrict__ rp, const int* __restrict__ col,
                               const uint32* __restrict__ X1, uint32* __restrict__ H2,
                               int h) {
    int g, nb;
    if (!xcd_map(blockIdx.x, NB / 4, g, nb)) return;
    int node = nb * 4 + (threadIdx.x >> 6);
    int lane = threadIdx.x & 63;
    int sub = lane >> 5;            // which edge of the pair
    int w = lane & 31;              // word within the 128B half
    const int* rpg = rp + g * (NB + 1);
    const int* clg = col + (size_t)g * N_EDGES;
    int beg = rpg[node], end = rpg[node + 1];
    const uint32* Bg = X1 + (size_t)g * NB * 64 + h * 32;
    float ax = 0.0f, ay = 0.0f;
    for (int j = beg + sub; j < end; j += 2) {
        uint32 v = Bg[(size_t)clg[j] * 64 + w];
        ax += bf2f(v & 0xffffu); ay += bf2f(v >> 16);
    }
    ax += __shfl_xor(ax, 32);
    ay += __shfl_xor(ay, 32);
    if (sub == 0) {
        uint32 sv = Bg[(size_t)node * 64 + w];
        ax += bf2f(sv & 0xffffu); ay += bf2f(sv >> 16);
        H2[(size_t)(g * NB + node) * 64 + h * 32 + w] = pack2(ax, ay);
    }
}

// ---- MFMA MLP2: x2 = relu(relu(h2@W21+b21)@W22+b22), pool-only ----
// block: 256 thr = 4 waves, 64 nodes; wave owns a private 16-row slab.
__launch_bounds__(256)
__global__ void mlp2_kernel(const uint32* __restrict__ H2,
                            const uint32* __restrict__ W21p, const float* __restrict__ b21,
                            const uint32* __restrict__ W22p, const float* __restrict__ b22,
                            float* __restrict__ gsum) {
    __shared__ uint32 tl[64 * 64];      // t tile, bf16, XOR-swizzled rows of 256B
    __shared__ float psum[HID];
    int g = blockIdx.y;
    int base = blockIdx.x * 64;
    int nvalid = NB - base; if (nvalid > 64) nvalid = 64;
    int tid = threadIdx.x;
    int wave = tid >> 6, l = tid & 63;
    int lq = l >> 4, lr = l & 15;
    if (tid < HID) psum[tid] = 0.0f;
    __syncthreads();

    // ---- GEMM1: C1 = h2 @ W21 (A from global, B frag-packed) ----
    f32x4 acc[8];
#pragma unroll
    for (int c = 0; c < 8; ++c) acc[c] = (f32x4){0.f, 0.f, 0.f, 0.f};
    int arow = wave * 16 + lr;
    int arowc = (arow < nvalid) ? arow : 0;   // clamp; masked at pool
    const uint32* h2row = H2 + ((size_t)g * NB + base + arowc) * 64;
#pragma unroll
    for (int t = 0; t < 4; ++t) {
        uint4 av = *(const uint4*)&h2row[t * 16 + lq * 4];
        bf16x8v af = __builtin_bit_cast(bf16x8v, av);
#pragma unroll
        for (int c = 0; c < 8; ++c) {
            uint4 bv = *(const uint4*)&W21p[((t * 8 + c) * 64 + l) * 4];
            acc[c] = __builtin_amdgcn_mfma_f32_16x16x32_bf16(
                af, __builtin_bit_cast(bf16x8v, bv), acc[c], 0, 0, 0);
        }
    }
    // ---- bias + relu -> t (bf16) in wave-private swizzled LDS ----
    unsigned short* tls = (unsigned short*)tl;
#pragma unroll
    for (int c = 0; c < 8; ++c) {
        int colv = c * 16 + lr;
        float bb = b21[colv];
#pragma unroll
        for (int q = 0; q < 4; ++q) {
            int row = wave * 16 + lq * 4 + q;
            float v = fmaxf(acc[c][q] + bb, 0.0f);
            int byte = row * 256 + ((colv * 2) ^ ((row & 7) << 4));
            tls[byte >> 1] = f2bf(v);
        }
    }
    // ---- GEMM2: C2 = t @ W22 (A from swizzled LDS; wave-private, no barrier) ----
    f32x4 acc2[8];
#pragma unroll
    for (int c = 0; c < 8; ++c) acc2[c] = (f32x4){0.f, 0.f, 0.f, 0.f};
#pragma unroll
    for (int t = 0; t < 4; ++t) {
        int rbyte = arow * 256 + (((t * 64 + lq * 16)) ^ ((arow & 7) << 4));
        uint4 av = *(const uint4*)((const char*)tl + rbyte);
        bf16x8v af = __builtin_bit_cast(bf16x8v, av);
#pragma unroll
        for (int c = 0; c < 8; ++c) {
            uint4 bv = *(const uint4*)&W22p[((t * 8 + c) * 64 + l) * 4];
            acc2[c] = __builtin_amdgcn_mfma_f32_16x16x32_bf16(
                af, __builtin_bit_cast(bf16x8v, bv), acc2[c], 0, 0, 0);
        }
    }
    // ---- pool: relu + row-masked column sums ----
#pragma unroll
    for (int c = 0; c < 8; ++c) {
        float bb = b22[c * 16 + lr];
        float s = 0.0f;
#pragma unroll
        for (int q = 0; q < 4; ++q) {
            int row = wave * 16 + lq * 4 + q;
            float v = fmaxf(acc2[c][q] + bb, 0.0f);
            s += (row < nvalid) ? v : 0.0f;
        }
        s += __shfl_xor(s, 16);
        s += __shfl_xor(s, 32);
        if (lq == 0) atomicAdd(&psum[c * 16 + lr], s);
    }
    __syncthreads();
    if (tid < HID) atomicAdd(&gsum[g * HID + tid], psum[tid]);
}

// ---- triplet head ----
__global__ void final_kernel(const float* __restrict__ gsum, const float* __restrict__ Wf,
                             const float* __restrict__ bf, float* __restrict__ out) {
    int tid = threadIdx.x;  // 384
    int g = tid >> 7;
    int o = tid & 127;
    float acc = bf[o];
    for (int k = 0; k < HID; ++k)
        acc += gsum[g * HID + k] * Wf[k * HID + o];
    out[g * HID + o] = acc;
}

extern "C" void kernel_launch(void* const* d_in, const int* in_sizes, int n_in,
                              void* d_out, int out_size, void* d_ws, size_t ws_size,
                              hipStream_t stream) {
    const float* xa = (const float*)d_in[0];
    const int*   ea = (const int*)d_in[1];
    const float* xp = (const float*)d_in[2];
    const int*   ep = (const int*)d_in[3];
    const float* xn = (const float*)d_in[4];
    const int*   en = (const int*)d_in[5];
    const float* W11 = (const float*)d_in[6];
    const float* b11 = (const float*)d_in[7];
    const float* W12 = (const float*)d_in[8];
    const float* b12 = (const float*)d_in[9];
    const float* W21 = (const float*)d_in[10];
    const float* b21 = (const float*)d_in[11];
    const float* W22 = (const float*)d_in[12];
    const float* b22 = (const float*)d_in[13];
    const float* Wf  = (const float*)d_in[14];
    const float* bf  = (const float*)d_in[15];

    float*  ws    = (float*)d_ws;
    uint32* X1    = (uint32*)(ws + X1_OFF);
    uint32* H2    = (uint32*)(ws + H2_OFF);
    int*    col   = (int*)(ws + COL_OFF);
    int*    rp    = (int*)(ws + RP_OFF);
    float*  gsum  = ws + GSUM_OFF;
    float*  ts    = ws + TS_OFF;
    float*  UV    = ws + UV_OFF;
    uint32* gh    = (uint32*)(ws + GH_OFF);
    uint32* offsP = (uint32*)(ws + OFFS_OFF);
    int*    tot   = (int*)(ws + TOT_OFF);
    uint32* W21p  = (uint32*)(ws + W21P_OFF);
    uint32* W22p  = (uint32*)(ws + W22P_OFF);
    float*  out   = (float*)d_out;

    prep_kernel<<<1, 128, 0, stream>>>(W11, b11, W12, b12, W21, W22, ts, UV, W21p, W22p, gsum);
    hist_kernel<<<dim3(BPG, 3), 256, 0, stream>>>(ea, ep, en, gh);
    colscan_kernel<<<dim3((NPAIR + 255) / 256, 3), 256, 0, stream>>>(gh, offsP, tot);
    scan_kernel<<<3, 256, 0, stream>>>(tot, rp);
    fill_kernel<<<GRID_FOR(BPG), 256, 0, stream>>>(ea, ep, en, rp, offsP, col);
    l1_kernel<<<dim3(NB / 4, 3), 256, 0, stream>>>(xa, xp, xn, rp, col, ts, UV, X1);
    gather2_kernel<<<GRID_FOR(NB / 4), 256, 0, stream>>>(rp, col, X1, H2, 0);
    gather2_kernel<<<GRID_FOR(NB / 4), 256, 0, stream>>>(rp, col, X1, H2, 1);
    mlp2_kernel<<<dim3(NBLK64, 3), 256, 0, stream>>>(H2, W21p, b21, W22p, b22, gsum);
    final_kernel<<<1, 384, 0, stream>>>(gsum, Wf, bf, out);
}

// Round 6
// 284.724 us; speedup vs baseline: 1.3762x; 1.2545x over previous
//
#include <hip/hip_runtime.h>

#define N_NODES 20000
#define N_EDGES 600000
#define HID 128
#define NB N_NODES
#define NBLK64 313                  // ceil(20000/64)
#define BPG 40                      // CSR-build blocks per graph
#define CHUNK (N_EDGES / BPG)       // 15000
#define NPAIR (NB / 2)              // 10000

typedef unsigned int uint32;
typedef __attribute__((ext_vector_type(8))) short bf16x8v;   // 8 bf16 in 4 VGPRs
typedef __attribute__((ext_vector_type(4))) float f32x4;

// ---------------- workspace layout (4-byte words) ----------------
#define X1_OFF   0                  // x1 bf16-packed: 3*20000*64
#define H2_OFF   3840000            // h2 bf16-packed: 3*20000*64
#define COL_OFF  7680000            // 3*600000 int
#define RP_OFF   9480000            // 3*20001 int
#define GSUM_OFF 9540008            // 3*128 f32
#define TS_OFF   9540392            // 128 f32 sorted breakpoints
#define UV_OFF   9540520            // 129 x (U[128],V[128]) f32 = 33024
#define GH_OFF   9573544            // 3*40*10000 packed u32
#define OFFS_OFF 10773544           // 3*40*10000 packed u32
#define TOT_OFF  11973544           // 3*20000 int
#define W21P_OFF 12033544           // 128*128 bf16 frag-packed = 8192 words
#define W22P_OFF 12041736           // 8192 words
// end 12,049,928 words = 48.2 MB

static __device__ inline unsigned short f2bf(float f) {
    uint32 u = __float_as_uint(f);
    return (unsigned short)((u + 0x7fffu + ((u >> 16) & 1u)) >> 16);
}
static __device__ inline float bf2f(uint32 lo16) {
    return __uint_as_float(lo16 << 16);
}
static __device__ inline uint32 pack2(float a, float b) {
    return (uint32)f2bf(a) | ((uint32)f2bf(b) << 16);
}

// ---- prep: relu-breakpoint tables for L1 + bf16 frag-packed W21/W22 ----
__launch_bounds__(128)
__global__ void prep_kernel(const float* __restrict__ W11, const float* __restrict__ b11,
                            const float* __restrict__ W12, const float* __restrict__ b12,
                            const float* __restrict__ W21, const float* __restrict__ W22,
                            float* __restrict__ ts, float* __restrict__ UV,
                            uint32* __restrict__ W21p, uint32* __restrict__ W22p,
                            float* __restrict__ gsum) {
    __shared__ float tsh[128], tss[128], wsh[128], bsh[128];
    __shared__ int order[128];
    __shared__ signed char sgn[128];
    int tid = threadIdx.x;   // 128
    float w = W11[tid], b = b11[tid];
    wsh[tid] = w; bsh[tid] = b;
    float t; int sg;
    if (w > 0.0f)      { t = -b / w; sg = 1; }
    else if (w < 0.0f) { t = -b / w; sg = -1; }
    else               { t = 3.0e38f; sg = 0; }
    tsh[tid] = t; sgn[tid] = (signed char)sg;
    __syncthreads();
    int rank = 0;
    for (int j = 0; j < 128; ++j) {
        float tj = tsh[j];
        if (tj < t || (tj == t && j < tid)) ++rank;
    }
    tss[rank] = t; order[rank] = tid;
    __syncthreads();
    ts[tid] = tss[tid];
    float u = 0.0f, v = b12[tid];
    for (int k = 0; k < 128; ++k) {
        float wk = wsh[k];
        float w12 = W12[k * HID + tid];
        if (wk < 0.0f)                        { u += wk * w12; v += bsh[k] * w12; }
        else if (wk == 0.0f && bsh[k] > 0.0f) { v += bsh[k] * w12; }
    }
    UV[tid] = u; UV[128 + tid] = v;
    for (int p = 1; p <= 128; ++p) {
        int k = order[p - 1];
        float wk = wsh[k], bk = bsh[k];
        float w12 = W12[k * HID + tid];
        int s2 = sgn[k];
        if (s2 > 0)      { u += wk * w12; v += bk * w12; }
        else if (s2 < 0) { u -= wk * w12; v -= bk * w12; }
        UV[p * 256 + tid] = u; UV[p * 256 + 128 + tid] = v;
    }
    gsum[tid] = 0.0f; gsum[128 + tid] = 0.0f; gsum[256 + tid] = 0.0f;
    // frag-pack W21/W22 -> bf16. B-frag: lane l holds B[t*32+(l>>4)*8+j][c*16+(l&15)]
    for (int idx = tid; idx < 2048; idx += 128) {   // idx over (t,c,l)
        int tt = idx >> 9, c = (idx >> 6) & 7, l = idx & 63;
        int kbase = tt * 32 + (l >> 4) * 8;
        int colv = c * 16 + (l & 15);
#pragma unroll
        for (int jw = 0; jw < 4; ++jw) {
            float f0 = W21[(kbase + 2 * jw) * HID + colv];
            float f1 = W21[(kbase + 2 * jw + 1) * HID + colv];
            W21p[idx * 4 + jw] = pack2(f0, f1);
            f0 = W22[(kbase + 2 * jw) * HID + colv];
            f1 = W22[(kbase + 2 * jw + 1) * HID + colv];
            W22p[idx * 4 + jw] = pack2(f0, f1);
        }
    }
}

// ---- CSR build phase A: per-block LDS histogram (packed 2x u16) ----
__launch_bounds__(256)
__global__ void hist_kernel(const int* __restrict__ ea, const int* __restrict__ ep,
                            const int* __restrict__ en, uint32* __restrict__ gh) {
    __shared__ uint32 h[NPAIR];     // 40 KB
    int g = blockIdx.y, blk = blockIdx.x, tid = threadIdx.x;
    const int* e = (g == 0) ? ea : (g == 1) ? ep : en;
    for (int i = tid; i < NPAIR; i += 256) h[i] = 0;
    __syncthreads();
    int base = blk * CHUNK;
    for (int i = tid; i < CHUNK; i += 256) {
        int dst = e[N_EDGES + base + i];
        atomicAdd(&h[dst >> 1], 1u << ((dst & 1) * 16));
    }
    __syncthreads();
    uint32* out = gh + ((size_t)g * BPG + blk) * NPAIR;
    for (int i = tid; i < NPAIR; i += 256) out[i] = h[i];
}

// ---- phase B1: per-(block,bin) prefix (u16 pair packed) + per-bin totals ----
__launch_bounds__(256)
__global__ void colscan_kernel(const uint32* __restrict__ gh, uint32* __restrict__ offsP,
                               int* __restrict__ tot) {
    int g = blockIdx.y;
    int p = blockIdx.x * 256 + threadIdx.x;
    if (p >= NPAIR) return;
    const uint32* ghg = gh + (size_t)g * BPG * NPAIR;
    uint32* og = offsP + (size_t)g * BPG * NPAIR;
    uint32 runLo = 0, runHi = 0;
    for (int k = 0; k < BPG; ++k) {
        uint32 w = ghg[(size_t)k * NPAIR + p];
        og[(size_t)k * NPAIR + p] = runLo | (runHi << 16);
        runLo += w & 0xffffu;
        runHi += w >> 16;
    }
    tot[g * NB + 2 * p]     = (int)runLo;
    tot[g * NB + 2 * p + 1] = (int)runHi;
}

// ---- phase B2: exclusive scan of totals -> row_ptr ----
__global__ void scan_kernel(const int* __restrict__ tot, int* __restrict__ rp) {
    int g = blockIdx.x;
    int tid = threadIdx.x;                 // 256
    const int CH = (NB + 255) / 256;       // 79
    __shared__ int partial[256];
    int begin = tid * CH; if (begin > NB) begin = NB;
    int end = begin + CH; if (end > NB) end = NB;
    int s = 0;
    for (int i = begin; i < end; ++i) s += tot[g * NB + i];
    partial[tid] = s;
    __syncthreads();
    if (tid == 0) {
        int run = 0;
        for (int i = 0; i < 256; ++i) { int t = partial[i]; partial[i] = run; run += t; }
    }
    __syncthreads();
    int run = partial[tid];
    for (int i = begin; i < end; ++i) {
        rp[g * (NB + 1) + i] = run;
        run += tot[g * NB + i];
    }
    if (tid == 255) rp[g * (NB + 1) + NB] = run;
}

// ---- phase C: fill col[] via LDS rank counters; balanced plain grid ----
__launch_bounds__(256)
__global__ void fill_kernel(const int* __restrict__ ea, const int* __restrict__ ep,
                            const int* __restrict__ en, const int* __restrict__ rp,
                            const uint32* __restrict__ offsP, int* __restrict__ col) {
    __shared__ uint32 h[NPAIR];
    int g = blockIdx.y, blk = blockIdx.x, tid = threadIdx.x;
    const int* e = (g == 0) ? ea : (g == 1) ? ep : en;
    for (int i = tid; i < NPAIR; i += 256) h[i] = 0;
    __syncthreads();
    int base = blk * CHUNK;
    const int* rpg = rp + g * (NB + 1);
    const uint32* og = offsP + ((size_t)g * BPG + blk) * NPAIR;
    int* colg = col + (size_t)g * N_EDGES;
    for (int i = tid; i < CHUNK; i += 256) {
        int src = e[base + i];
        int dst = e[N_EDGES + base + i];
        uint32 old = atomicAdd(&h[dst >> 1], 1u << ((dst & 1) * 16));
        int rank = (int)((old >> ((dst & 1) * 16)) & 0xffffu);
        int offs = (int)((og[dst >> 1] >> ((dst & 1) * 16)) & 0xffffu);
        colg[rpg[dst] + offs + rank] = src;
    }
}

// ---- L1: scalar gather + pattern-table MLP1 -> x1 (bf16). wave per node ----
__launch_bounds__(256)
__global__ void l1_kernel(const float* __restrict__ xa, const float* __restrict__ xp,
                          const float* __restrict__ xn,
                          const int* __restrict__ rp, const int* __restrict__ col,
                          const float* __restrict__ ts, const float* __restrict__ UV,
                          uint32* __restrict__ X1) {
    __shared__ float tsh[128];
    int tid = threadIdx.x;
    if (tid < 128) tsh[tid] = ts[tid];
    __syncthreads();
    int g = blockIdx.y;
    const float* x = (g == 0) ? xa : (g == 1) ? xp : xn;
    int node = blockIdx.x * 4 + (tid >> 6);
    int lane = tid & 63;
    const int* rpg = rp + g * (NB + 1);
    const int* clg = col + (size_t)g * N_EDGES;
    int beg = rpg[node], end = rpg[node + 1];
    float s = 0.0f;
    for (int j = beg + lane; j < end; j += 64) s += x[clg[j]];
#pragma unroll
    for (int off = 32; off > 0; off >>= 1) s += __shfl_down(s, off);
    s = __shfl(s, 0);
    s += x[node];
    int lo = 0, hi = 128;
    while (lo < hi) { int mid = (lo + hi) >> 1; if (tsh[mid] < s) lo = mid + 1; else hi = mid; }
    const float* Up = UV + (size_t)lo * 256;
    float2 u = *(const float2*)&Up[lane * 2];
    float2 v = *(const float2*)&Up[128 + lane * 2];
    float r0 = fmaxf(fmaf(s, u.x, v.x), 0.0f);
    float r1 = fmaxf(fmaf(s, u.y, v.y), 0.0f);
    X1[(size_t)(g * NB + node) * 64 + lane] = pack2(r0, r1);
}

// ---- L2 aggregation, high-ILP half-row gather ----
// Task layout: XCDs 0-3 run (gA,hA), XCDs 4-7 run (gB,hB). Lane owns 8B of a
// 128B half-row (16 lanes/edge, 4 edges per wave-instr, 16 edges per main iter).
__launch_bounds__(256)
__global__ void gather2_kernel(const int* __restrict__ rp, const int* __restrict__ col,
                               const uint32* __restrict__ X1, uint32* __restrict__ H2,
                               int gA, int hA, int gB, int hB) {
    int b = blockIdx.x;
    int xcd = b & 7, slot = b >> 3;
    int g = (xcd >> 2) ? gB : gA;
    int h = (xcd >> 2) ? hB : hA;
    int nb = slot * 4 + (xcd & 3);            // 0..4999
    int node = nb * 4 + (threadIdx.x >> 6);
    int lane = threadIdx.x & 63;
    int sub = lane >> 4;                       // edge slot 0..3
    int w = lane & 15;                         // uint2 index within 128B half
    const int* rpg = rp + g * (NB + 1);
    const int* clg = col + (size_t)g * N_EDGES;
    int beg = rpg[node], end = rpg[node + 1];
    const uint32* Bg = X1 + (size_t)g * NB * 64 + h * 32;
    float a0 = 0.f, a1 = 0.f, a2 = 0.f, a3 = 0.f;
    int j = beg;
    for (; j + 16 <= end; j += 16) {           // 16 edges, 4 loads in flight/lane
        int jb = j + sub * 4;
        int c0 = clg[jb], c1 = clg[jb + 1], c2 = clg[jb + 2], c3 = clg[jb + 3];
        uint2 v0 = *(const uint2*)&Bg[(size_t)c0 * 64 + w * 2];
        uint2 v1 = *(const uint2*)&Bg[(size_t)c1 * 64 + w * 2];
        uint2 v2 = *(const uint2*)&Bg[(size_t)c2 * 64 + w * 2];
        uint2 v3 = *(const uint2*)&Bg[(size_t)c3 * 64 + w * 2];
        a0 += bf2f(v0.x & 0xffffu) + bf2f(v1.x & 0xffffu) + bf2f(v2.x & 0xffffu) + bf2f(v3.x & 0xffffu);
        a1 += bf2f(v0.x >> 16)     + bf2f(v1.x >> 16)     + bf2f(v2.x >> 16)     + bf2f(v3.x >> 16);
        a2 += bf2f(v0.y & 0xffffu) + bf2f(v1.y & 0xffffu) + bf2f(v2.y & 0xffffu) + bf2f(v3.y & 0xffffu);
        a3 += bf2f(v0.y >> 16)     + bf2f(v1.y >> 16)     + bf2f(v2.y >> 16)     + bf2f(v3.y >> 16);
    }
    for (; j + 4 <= end; j += 4) {             // 4 edges per iter
        int c0 = clg[j + sub];
        uint2 v0 = *(const uint2*)&Bg[(size_t)c0 * 64 + w * 2];
        a0 += bf2f(v0.x & 0xffffu); a1 += bf2f(v0.x >> 16);
        a2 += bf2f(v0.y & 0xffffu); a3 += bf2f(v0.y >> 16);
    }
    if (j + sub < end) {                       // masked tail (<4 edges)
        int c0 = clg[j + sub];
        uint2 v0 = *(const uint2*)&Bg[(size_t)c0 * 64 + w * 2];
        a0 += bf2f(v0.x & 0xffffu); a1 += bf2f(v0.x >> 16);
        a2 += bf2f(v0.y & 0xffffu); a3 += bf2f(v0.y >> 16);
    }
    a0 += __shfl_xor(a0, 16); a0 += __shfl_xor(a0, 32);
    a1 += __shfl_xor(a1, 16); a1 += __shfl_xor(a1, 32);
    a2 += __shfl_xor(a2, 16); a2 += __shfl_xor(a2, 32);
    a3 += __shfl_xor(a3, 16); a3 += __shfl_xor(a3, 32);
    if (sub == 0) {
        uint2 sv = *(const uint2*)&Bg[(size_t)node * 64 + w * 2];
        a0 += bf2f(sv.x & 0xffffu); a1 += bf2f(sv.x >> 16);
        a2 += bf2f(sv.y & 0xffffu); a3 += bf2f(sv.y >> 16);
        uint2 o; o.x = pack2(a0, a1); o.y = pack2(a2, a3);
        *(uint2*)&H2[(size_t)(g * NB + node) * 64 + h * 32 + w * 2] = o;
    }
}

// ---- MFMA MLP2: x2 = relu(relu(h2@W21+b21)@W22+b22), pool-only ----
__launch_bounds__(256)
__global__ void mlp2_kernel(const uint32* __restrict__ H2,
                            const uint32* __restrict__ W21p, const float* __restrict__ b21,
                            const uint32* __restrict__ W22p, const float* __restrict__ b22,
                            float* __restrict__ gsum) {
    __shared__ uint32 tl[64 * 64];      // t tile, bf16, XOR-swizzled rows of 256B
    __shared__ float psum[HID];
    int g = blockIdx.y;
    int base = blockIdx.x * 64;
    int nvalid = NB - base; if (nvalid > 64) nvalid = 64;
    int tid = threadIdx.x;
    int wave = tid >> 6, l = tid & 63;
    int lq = l >> 4, lr = l & 15;
    if (tid < HID) psum[tid] = 0.0f;
    __syncthreads();

    f32x4 acc[8];
#pragma unroll
    for (int c = 0; c < 8; ++c) acc[c] = (f32x4){0.f, 0.f, 0.f, 0.f};
    int arow = wave * 16 + lr;
    int arowc = (arow < nvalid) ? arow : 0;
    const uint32* h2row = H2 + ((size_t)g * NB + base + arowc) * 64;
#pragma unroll
    for (int t = 0; t < 4; ++t) {
        uint4 av = *(const uint4*)&h2row[t * 16 + lq * 4];
        bf16x8v af = __builtin_bit_cast(bf16x8v, av);
#pragma unroll
        for (int c = 0; c < 8; ++c) {
            uint4 bv = *(const uint4*)&W21p[((t * 8 + c) * 64 + l) * 4];
            acc[c] = __builtin_amdgcn_mfma_f32_16x16x32_bf16(
                af, __builtin_bit_cast(bf16x8v, bv), acc[c], 0, 0, 0);
        }
    }
    unsigned short* tls = (unsigned short*)tl;
#pragma unroll
    for (int c = 0; c < 8; ++c) {
        int colv = c * 16 + lr;
        float bb = b21[colv];
#pragma unroll
        for (int q = 0; q < 4; ++q) {
            int row = wave * 16 + lq * 4 + q;
            float v = fmaxf(acc[c][q] + bb, 0.0f);
            int byte = row * 256 + ((colv * 2) ^ ((row & 7) << 4));
            tls[byte >> 1] = f2bf(v);
        }
    }
    f32x4 acc2[8];
#pragma unroll
    for (int c = 0; c < 8; ++c) acc2[c] = (f32x4){0.f, 0.f, 0.f, 0.f};
#pragma unroll
    for (int t = 0; t < 4; ++t) {
        int rbyte = arow * 256 + (((t * 64 + lq * 16)) ^ ((arow & 7) << 4));
        uint4 av = *(const uint4*)((const char*)tl + rbyte);
        bf16x8v af = __builtin_bit_cast(bf16x8v, av);
#pragma unroll
        for (int c = 0; c < 8; ++c) {
            uint4 bv = *(const uint4*)&W22p[((t * 8 + c) * 64 + l) * 4];
            acc2[c] = __builtin_amdgcn_mfma_f32_16x16x32_bf16(
                af, __builtin_bit_cast(bf16x8v, bv), acc2[c], 0, 0, 0);
        }
    }
#pragma unroll
    for (int c = 0; c < 8; ++c) {
        float bb = b22[c * 16 + lr];
        float s = 0.0f;
#pragma unroll
        for (int q = 0; q < 4; ++q) {
            int row = wave * 16 + lq * 4 + q;
            float v = fmaxf(acc2[c][q] + bb, 0.0f);
            s += (row < nvalid) ? v : 0.0f;
        }
        s += __shfl_xor(s, 16);
        s += __shfl_xor(s, 32);
        if (lq == 0) atomicAdd(&psum[c * 16 + lr], s);
    }
    __syncthreads();
    if (tid < HID) atomicAdd(&gsum[g * HID + tid], psum[tid]);
}

// ---- triplet head ----
__global__ void final_kernel(const float* __restrict__ gsum, const float* __restrict__ Wf,
                             const float* __restrict__ bf, float* __restrict__ out) {
    int tid = threadIdx.x;  // 384
    int g = tid >> 7;
    int o = tid & 127;
    float acc = bf[o];
    for (int k = 0; k < HID; ++k)
        acc += gsum[g * HID + k] * Wf[k * HID + o];
    out[g * HID + o] = acc;
}

extern "C" void kernel_launch(void* const* d_in, const int* in_sizes, int n_in,
                              void* d_out, int out_size, void* d_ws, size_t ws_size,
                              hipStream_t stream) {
    const float* xa = (const float*)d_in[0];
    const int*   ea = (const int*)d_in[1];
    const float* xp = (const float*)d_in[2];
    const int*   ep = (const int*)d_in[3];
    const float* xn = (const float*)d_in[4];
    const int*   en = (const int*)d_in[5];
    const float* W11 = (const float*)d_in[6];
    const float* b11 = (const float*)d_in[7];
    const float* W12 = (const float*)d_in[8];
    const float* b12 = (const float*)d_in[9];
    const float* W21 = (const float*)d_in[10];
    const float* b21 = (const float*)d_in[11];
    const float* W22 = (const float*)d_in[12];
    const float* b22 = (const float*)d_in[13];
    const float* Wf  = (const float*)d_in[14];
    const float* bf  = (const float*)d_in[15];

    float*  ws    = (float*)d_ws;
    uint32* X1    = (uint32*)(ws + X1_OFF);
    uint32* H2    = (uint32*)(ws + H2_OFF);
    int*    col   = (int*)(ws + COL_OFF);
    int*    rp    = (int*)(ws + RP_OFF);
    float*  gsum  = ws + GSUM_OFF;
    float*  ts    = ws + TS_OFF;
    float*  UV    = ws + UV_OFF;
    uint32* gh    = (uint32*)(ws + GH_OFF);
    uint32* offsP = (uint32*)(ws + OFFS_OFF);
    int*    tot   = (int*)(ws + TOT_OFF);
    uint32* W21p  = (uint32*)(ws + W21P_OFF);
    uint32* W22p  = (uint32*)(ws + W22P_OFF);
    float*  out   = (float*)d_out;

    prep_kernel<<<1, 128, 0, stream>>>(W11, b11, W12, b12, W21, W22, ts, UV, W21p, W22p, gsum);
    hist_kernel<<<dim3(BPG, 3), 256, 0, stream>>>(ea, ep, en, gh);
    colscan_kernel<<<dim3((NPAIR + 255) / 256, 3), 256, 0, stream>>>(gh, offsP, tot);
    scan_kernel<<<3, 256, 0, stream>>>(tot, rp);
    fill_kernel<<<dim3(BPG, 3), 256, 0, stream>>>(ea, ep, en, rp, offsP, col);
    l1_kernel<<<dim3(NB / 4, 3), 256, 0, stream>>>(xa, xp, xn, rp, col, ts, UV, X1);
    // 3 balanced phases x 2 tasks x 4 XCDs; per-XCD working set 2.56MB (L2-resident)
    gather2_kernel<<<10000, 256, 0, stream>>>(rp, col, X1, H2, 0, 0, 1, 0);
    gather2_kernel<<<10000, 256, 0, stream>>>(rp, col, X1, H2, 2, 0, 2, 1);
    gather2_kernel<<<10000, 256, 0, stream>>>(rp, col, X1, H2, 0, 1, 1, 1);
    mlp2_kernel<<<dim3(NBLK64, 3), 256, 0, stream>>>(H2, W21p, b21, W22p, b22, gsum);
    final_kernel<<<1, 384, 0, stream>>>(gsum, Wf, bf, out);
}

// Round 7
// 283.478 us; speedup vs baseline: 1.3823x; 1.0044x over previous
//
#include <hip/hip_runtime.h>

#define N_NODES 20000
#define N_EDGES 600000
#define HID 128
#define NB N_NODES
#define NBLK64 313                  // ceil(20000/64)
#define BPG 160                     // CSR-build blocks per graph
#define CHUNK (N_EDGES / BPG)       // 3750
#define NPAIR (NB / 2)              // 10000
#define NQUAD (NB / 4)              // 5000 (u8-packed histogram words)

typedef unsigned int uint32;
typedef __attribute__((ext_vector_type(8))) short bf16x8v;   // 8 bf16 in 4 VGPRs
typedef __attribute__((ext_vector_type(4))) float f32x4;

// ---------------- workspace layout (4-byte words) ----------------
// CSR-build scratch (gh/offsP/tot) is DEAD before l1/gather2 write X1/H2,
// so it aliases the X1/H2 region (strictly stream-ordered).
#define GH_OFF   0                  // 3*160*5000 u32 (4x u8 counts)   [aliases X1]
#define OFFS_OFF 2400000            // 3*160*10000 u32 (2x u16 prefix) [aliases X1/H2]
#define TOT_OFF  7200000            // 3*20000 int                     [aliases H2]
#define X1_OFF   0                  // x1 bf16-packed: 3*20000*64
#define H2_OFF   3840000            // h2 bf16-packed: 3*20000*64
#define COL_OFF  7680000            // 3*600000 int
#define RP_OFF   9480000            // 3*20001 int
#define GSUM_OFF 9540008            // 3*128 f32
#define TS_OFF   9540392            // 128 f32 sorted breakpoints
#define UV_OFF   9540520            // 129 x (U[128],V[128]) f32 = 33024
#define W21P_OFF 9573544            // 128*128 bf16 frag-packed = 8192 words
#define W22P_OFF 9581736            // 8192 words
// end 9,589,928 words = 38.4 MB

static __device__ inline unsigned short f2bf(float f) {
    uint32 u = __float_as_uint(f);
    return (unsigned short)((u + 0x7fffu + ((u >> 16) & 1u)) >> 16);
}
static __device__ inline float bf2f(uint32 lo16) {
    return __uint_as_float(lo16 << 16);
}
static __device__ inline uint32 pack2(float a, float b) {
    return (uint32)f2bf(a) | ((uint32)f2bf(b) << 16);
}

// ---- prep: relu-breakpoint tables for L1 + bf16 frag-packed W21/W22 ----
__launch_bounds__(128)
__global__ void prep_kernel(const float* __restrict__ W11, const float* __restrict__ b11,
                            const float* __restrict__ W12, const float* __restrict__ b12,
                            const float* __restrict__ W21, const float* __restrict__ W22,
                            float* __restrict__ ts, float* __restrict__ UV,
                            uint32* __restrict__ W21p, uint32* __restrict__ W22p,
                            float* __restrict__ gsum) {
    __shared__ float tsh[128], tss[128], wsh[128], bsh[128];
    __shared__ int order[128];
    __shared__ signed char sgn[128];
    int tid = threadIdx.x;   // 128
    float w = W11[tid], b = b11[tid];
    wsh[tid] = w; bsh[tid] = b;
    float t; int sg;
    if (w > 0.0f)      { t = -b / w; sg = 1; }
    else if (w < 0.0f) { t = -b / w; sg = -1; }
    else               { t = 3.0e38f; sg = 0; }
    tsh[tid] = t; sgn[tid] = (signed char)sg;
    __syncthreads();
    int rank = 0;
    for (int j = 0; j < 128; ++j) {
        float tj = tsh[j];
        if (tj < t || (tj == t && j < tid)) ++rank;
    }
    tss[rank] = t; order[rank] = tid;
    __syncthreads();
    ts[tid] = tss[tid];
    float u = 0.0f, v = b12[tid];
    for (int k = 0; k < 128; ++k) {
        float wk = wsh[k];
        float w12 = W12[k * HID + tid];
        if (wk < 0.0f)                        { u += wk * w12; v += bsh[k] * w12; }
        else if (wk == 0.0f && bsh[k] > 0.0f) { v += bsh[k] * w12; }
    }
    UV[tid] = u; UV[128 + tid] = v;
    for (int p = 1; p <= 128; ++p) {
        int k = order[p - 1];
        float wk = wsh[k], bk = bsh[k];
        float w12 = W12[k * HID + tid];
        int s2 = sgn[k];
        if (s2 > 0)      { u += wk * w12; v += bk * w12; }
        else if (s2 < 0) { u -= wk * w12; v -= bk * w12; }
        UV[p * 256 + tid] = u; UV[p * 256 + 128 + tid] = v;
    }
    gsum[tid] = 0.0f; gsum[128 + tid] = 0.0f; gsum[256 + tid] = 0.0f;
    // frag-pack W21/W22 -> bf16. B-frag: lane l holds B[t*32+(l>>4)*8+j][c*16+(l&15)]
    for (int idx = tid; idx < 2048; idx += 128) {   // idx over (t,c,l)
        int tt = idx >> 9, c = (idx >> 6) & 7, l = idx & 63;
        int kbase = tt * 32 + (l >> 4) * 8;
        int colv = c * 16 + (l & 15);
#pragma unroll
        for (int jw = 0; jw < 4; ++jw) {
            float f0 = W21[(kbase + 2 * jw) * HID + colv];
            float f1 = W21[(kbase + 2 * jw + 1) * HID + colv];
            W21p[idx * 4 + jw] = pack2(f0, f1);
            f0 = W22[(kbase + 2 * jw) * HID + colv];
            f1 = W22[(kbase + 2 * jw + 1) * HID + colv];
            W22p[idx * 4 + jw] = pack2(f0, f1);
        }
    }
}

// ---- CSR phase A: per-block LDS histogram, u8-packed (20KB) ----
__launch_bounds__(256)
__global__ void hist_kernel(const int* __restrict__ ea, const int* __restrict__ ep,
                            const int* __restrict__ en, uint32* __restrict__ gh) {
    __shared__ uint32 h[NQUAD];     // 20 KB
    int g = blockIdx.y, blk = blockIdx.x, tid = threadIdx.x;
    const int* e = (g == 0) ? ea : (g == 1) ? ep : en;
    for (int i = tid; i < NQUAD; i += 256) h[i] = 0;
    __syncthreads();
    int base = blk * CHUNK;
    for (int i = tid; i < CHUNK; i += 256) {
        int dst = e[N_EDGES + base + i];
        atomicAdd(&h[dst >> 2], 1u << ((dst & 3) * 8));   // counts << 256 per chunk
    }
    __syncthreads();
    uint32* out = gh + ((size_t)g * BPG + blk) * NQUAD;
    for (int i = tid; i < NQUAD; i += 256) out[i] = h[i];
}

// ---- phase B1: per-(block,pair) u16 prefixes + per-bin totals ----
__launch_bounds__(256)
__global__ void colscan_kernel(const uint32* __restrict__ gh, uint32* __restrict__ offsP,
                               int* __restrict__ tot) {
    int g = blockIdx.y;
    int p = blockIdx.x * 256 + threadIdx.x;   // pair index (nodes 2p, 2p+1)
    if (p >= NPAIR) return;
    const uint32* ghg = gh + (size_t)g * BPG * NQUAD;
    uint32* og = offsP + (size_t)g * BPG * NPAIR;
    int sh = (p & 1) * 16;                     // byte offset of node 2p in its word
    uint32 runLo = 0, runHi = 0;
    for (int k = 0; k < BPG; ++k) {
        uint32 w = ghg[(size_t)k * NQUAD + (p >> 1)] >> sh;
        og[(size_t)k * NPAIR + p] = runLo | (runHi << 16);
        runLo += w & 0xffu;
        runHi += (w >> 8) & 0xffu;
    }
    tot[g * NB + 2 * p]     = (int)runLo;
    tot[g * NB + 2 * p + 1] = (int)runHi;
}

// ---- phase B2: exclusive scan of totals -> row_ptr ----
__global__ void scan_kernel(const int* __restrict__ tot, int* __restrict__ rp) {
    int g = blockIdx.x;
    int tid = threadIdx.x;                 // 256
    const int CH = (NB + 255) / 256;       // 79
    __shared__ int partial[256];
    int begin = tid * CH; if (begin > NB) begin = NB;
    int end = begin + CH; if (end > NB) end = NB;
    int s = 0;
    for (int i = begin; i < end; ++i) s += tot[g * NB + i];
    partial[tid] = s;
    __syncthreads();
    if (tid == 0) {
        int run = 0;
        for (int i = 0; i < 256; ++i) { int t = partial[i]; partial[i] = run; run += t; }
    }
    __syncthreads();
    int run = partial[tid];
    for (int i = begin; i < end; ++i) {
        rp[g * (NB + 1) + i] = run;
        run += tot[g * NB + i];
    }
    if (tid == 255) rp[g * (NB + 1) + NB] = run;
}

// ---- phase C: fill col[] via u8 LDS rank counters ----
__launch_bounds__(256)
__global__ void fill_kernel(const int* __restrict__ ea, const int* __restrict__ ep,
                            const int* __restrict__ en, const int* __restrict__ rp,
                            const uint32* __restrict__ offsP, int* __restrict__ col) {
    __shared__ uint32 h[NQUAD];     // 20 KB
    int g = blockIdx.y, blk = blockIdx.x, tid = threadIdx.x;
    const int* e = (g == 0) ? ea : (g == 1) ? ep : en;
    for (int i = tid; i < NQUAD; i += 256) h[i] = 0;
    __syncthreads();
    int base = blk * CHUNK;
    const int* rpg = rp + g * (NB + 1);
    const uint32* og = offsP + ((size_t)g * BPG + blk) * NPAIR;
    int* colg = col + (size_t)g * N_EDGES;
    for (int i = tid; i < CHUNK; i += 256) {
        int src = e[base + i];
        int dst = e[N_EDGES + base + i];
        uint32 old = atomicAdd(&h[dst >> 2], 1u << ((dst & 3) * 8));
        int rank = (int)((old >> ((dst & 3) * 8)) & 0xffu);
        int offs = (int)((og[dst >> 1] >> ((dst & 1) * 16)) & 0xffffu);
        colg[rpg[dst] + offs + rank] = src;
    }
}

// ---- L1: scalar gather + pattern-table MLP1 -> x1 (bf16). wave per node ----
__launch_bounds__(256)
__global__ void l1_kernel(const float* __restrict__ xa, const float* __restrict__ xp,
                          const float* __restrict__ xn,
                          const int* __restrict__ rp, const int* __restrict__ col,
                          const float* __restrict__ ts, const float* __restrict__ UV,
                          uint32* __restrict__ X1) {
    __shared__ float tsh[128];
    int tid = threadIdx.x;
    if (tid < 128) tsh[tid] = ts[tid];
    __syncthreads();
    int g = blockIdx.y;
    const float* x = (g == 0) ? xa : (g == 1) ? xp : xn;
    int node = blockIdx.x * 4 + (tid >> 6);
    int lane = tid & 63;
    const int* rpg = rp + g * (NB + 1);
    const int* clg = col + (size_t)g * N_EDGES;
    int beg = rpg[node], end = rpg[node + 1];
    float s = 0.0f;
    for (int j = beg + lane; j < end; j += 64) s += x[clg[j]];
#pragma unroll
    for (int off = 32; off > 0; off >>= 1) s += __shfl_down(s, off);
    s = __shfl(s, 0);
    s += x[node];
    int lo = 0, hi = 128;
    while (lo < hi) { int mid = (lo + hi) >> 1; if (tsh[mid] < s) lo = mid + 1; else hi = mid; }
    const float* Up = UV + (size_t)lo * 256;
    float2 u = *(const float2*)&Up[lane * 2];
    float2 v = *(const float2*)&Up[128 + lane * 2];
    float r0 = fmaxf(fmaf(s, u.x, v.x), 0.0f);
    float r1 = fmaxf(fmaf(s, u.y, v.y), 0.0f);
    X1[(size_t)(g * NB + node) * 64 + lane] = pack2(r0, r1);
}

// ---- L2 aggregation, high-ILP half-row gather ----
// XCDs 0-3 run (gA,hA), XCDs 4-7 run (gB,hB). Lane owns 8B of a 128B half-row
// (16 lanes/edge, 4 edges per wave-instr, 16 edges per main iter).
__launch_bounds__(256)
__global__ void gather2_kernel(const int* __restrict__ rp, const int* __restrict__ col,
                               const uint32* __restrict__ X1, uint32* __restrict__ H2,
                               int gA, int hA, int gB, int hB) {
    int b = blockIdx.x;
    int xcd = b & 7, slot = b >> 3;
    int g = (xcd >> 2) ? gB : gA;
    int h = (xcd >> 2) ? hB : hA;
    int nb = slot * 4 + (xcd & 3);            // 0..4999
    int node = nb * 4 + (threadIdx.x >> 6);
    int lane = threadIdx.x & 63;
    int sub = lane >> 4;                       // edge slot 0..3
    int w = lane & 15;                         // uint2 index within 128B half
    const int* rpg = rp + g * (NB + 1);
    const int* clg = col + (size_t)g * N_EDGES;
    int beg = rpg[node], end = rpg[node + 1];
    const uint32* Bg = X1 + (size_t)g * NB * 64 + h * 32;
    float a0 = 0.f, a1 = 0.f, a2 = 0.f, a3 = 0.f;
    int j = beg;
    for (; j + 16 <= end; j += 16) {           // 16 edges, 4 loads in flight/lane
        int jb = j + sub * 4;
        int c0 = clg[jb], c1 = clg[jb + 1], c2 = clg[jb + 2], c3 = clg[jb + 3];
        uint2 v0 = *(const uint2*)&Bg[(size_t)c0 * 64 + w * 2];
        uint2 v1 = *(const uint2*)&Bg[(size_t)c1 * 64 + w * 2];
        uint2 v2 = *(const uint2*)&Bg[(size_t)c2 * 64 + w * 2];
        uint2 v3 = *(const uint2*)&Bg[(size_t)c3 * 64 + w * 2];
        a0 += bf2f(v0.x & 0xffffu) + bf2f(v1.x & 0xffffu) + bf2f(v2.x & 0xffffu) + bf2f(v3.x & 0xffffu);
        a1 += bf2f(v0.x >> 16)     + bf2f(v1.x >> 16)     + bf2f(v2.x >> 16)     + bf2f(v3.x >> 16);
        a2 += bf2f(v0.y & 0xffffu) + bf2f(v1.y & 0xffffu) + bf2f(v2.y & 0xffffu) + bf2f(v3.y & 0xffffu);
        a3 += bf2f(v0.y >> 16)     + bf2f(v1.y >> 16)     + bf2f(v2.y >> 16)     + bf2f(v3.y >> 16);
    }
    for (; j + 4 <= end; j += 4) {             // 4 edges per iter
        int c0 = clg[j + sub];
        uint2 v0 = *(const uint2*)&Bg[(size_t)c0 * 64 + w * 2];
        a0 += bf2f(v0.x & 0xffffu); a1 += bf2f(v0.x >> 16);
        a2 += bf2f(v0.y & 0xffffu); a3 += bf2f(v0.y >> 16);
    }
    if (j + sub < end) {                       // masked tail (<4 edges)
        int c0 = clg[j + sub];
        uint2 v0 = *(const uint2*)&Bg[(size_t)c0 * 64 + w * 2];
        a0 += bf2f(v0.x & 0xffffu); a1 += bf2f(v0.x >> 16);
        a2 += bf2f(v0.y & 0xffffu); a3 += bf2f(v0.y >> 16);
    }
    a0 += __shfl_xor(a0, 16); a0 += __shfl_xor(a0, 32);
    a1 += __shfl_xor(a1, 16); a1 += __shfl_xor(a1, 32);
    a2 += __shfl_xor(a2, 16); a2 += __shfl_xor(a2, 32);
    a3 += __shfl_xor(a3, 16); a3 += __shfl_xor(a3, 32);
    if (sub == 0) {
        uint2 sv = *(const uint2*)&Bg[(size_t)node * 64 + w * 2];
        a0 += bf2f(sv.x & 0xffffu); a1 += bf2f(sv.x >> 16);
        a2 += bf2f(sv.y & 0xffffu); a3 += bf2f(sv.y >> 16);
        uint2 o; o.x = pack2(a0, a1); o.y = pack2(a2, a3);
        *(uint2*)&H2[(size_t)(g * NB + node) * 64 + h * 32 + w * 2] = o;
    }
}

// ---- MFMA MLP2: x2 = relu(relu(h2@W21+b21)@W22+b22), pool-only ----
__launch_bounds__(256)
__global__ void mlp2_kernel(const uint32* __restrict__ H2,
                            const uint32* __restrict__ W21p, const float* __restrict__ b21,
                            const uint32* __restrict__ W22p, const float* __restrict__ b22,
                            float* __restrict__ gsum) {
    __shared__ uint32 tl[64 * 64];      // t tile, bf16, XOR-swizzled rows of 256B
    __shared__ float psum[HID];
    int g = blockIdx.y;
    int base = blockIdx.x * 64;
    int nvalid = NB - base; if (nvalid > 64) nvalid = 64;
    int tid = threadIdx.x;
    int wave = tid >> 6, l = tid & 63;
    int lq = l >> 4, lr = l & 15;
    if (tid < HID) psum[tid] = 0.0f;
    __syncthreads();

    f32x4 acc[8];
#pragma unroll
    for (int c = 0; c < 8; ++c) acc[c] = (f32x4){0.f, 0.f, 0.f, 0.f};
    int arow = wave * 16 + lr;
    int arowc = (arow < nvalid) ? arow : 0;
    const uint32* h2row = H2 + ((size_t)g * NB + base + arowc) * 64;
#pragma unroll
    for (int t = 0; t < 4; ++t) {
        uint4 av = *(const uint4*)&h2row[t * 16 + lq * 4];
        bf16x8v af = __builtin_bit_cast(bf16x8v, av);
#pragma unroll
        for (int c = 0; c < 8; ++c) {
            uint4 bv = *(const uint4*)&W21p[((t * 8 + c) * 64 + l) * 4];
            acc[c] = __builtin_amdgcn_mfma_f32_16x16x32_bf16(
                af, __builtin_bit_cast(bf16x8v, bv), acc[c], 0, 0, 0);
        }
    }
    unsigned short* tls = (unsigned short*)tl;
#pragma unroll
    for (int c = 0; c < 8; ++c) {
        int colv = c * 16 + lr;
        float bb = b21[colv];
#pragma unroll
        for (int q = 0; q < 4; ++q) {
            int row = wave * 16 + lq * 4 + q;
            float v = fmaxf(acc[c][q] + bb, 0.0f);
            int byte = row * 256 + ((colv * 2) ^ ((row & 7) << 4));
            tls[byte >> 1] = f2bf(v);
        }
    }
    f32x4 acc2[8];
#pragma unroll
    for (int c = 0; c < 8; ++c) acc2[c] = (f32x4){0.f, 0.f, 0.f, 0.f};
#pragma unroll
    for (int t = 0; t < 4; ++t) {
        int rbyte = arow * 256 + (((t * 64 + lq * 16)) ^ ((arow & 7) << 4));
        uint4 av = *(const uint4*)((const char*)tl + rbyte);
        bf16x8v af = __builtin_bit_cast(bf16x8v, av);
#pragma unroll
        for (int c = 0; c < 8; ++c) {
            uint4 bv = *(const uint4*)&W22p[((t * 8 + c) * 64 + l) * 4];
            acc2[c] = __builtin_amdgcn_mfma_f32_16x16x32_bf16(
                af, __builtin_bit_cast(bf16x8v, bv), acc2[c], 0, 0, 0);
        }
    }
#pragma unroll
    for (int c = 0; c < 8; ++c) {
        float bb = b22[c * 16 + lr];
        float s = 0.0f;
#pragma unroll
        for (int q = 0; q < 4; ++q) {
            int row = wave * 16 + lq * 4 + q;
            float v = fmaxf(acc2[c][q] + bb, 0.0f);
            s += (row < nvalid) ? v : 0.0f;
        }
        s += __shfl_xor(s, 16);
        s += __shfl_xor(s, 32);
        if (lq == 0) atomicAdd(&psum[c * 16 + lr], s);
    }
    __syncthreads();
    if (tid < HID) atomicAdd(&gsum[g * HID + tid], psum[tid]);
}

// ---- triplet head ----
__global__ void final_kernel(const float* __restrict__ gsum, const float* __restrict__ Wf,
                             const float* __restrict__ bf, float* __restrict__ out) {
    int tid = threadIdx.x;  // 384
    int g = tid >> 7;
    int o = tid & 127;
    float acc = bf[o];
    for (int k = 0; k < HID; ++k)
        acc += gsum[g * HID + k] * Wf[k * HID + o];
    out[g * HID + o] = acc;
}

extern "C" void kernel_launch(void* const* d_in, const int* in_sizes, int n_in,
                              void* d_out, int out_size, void* d_ws, size_t ws_size,
                              hipStream_t stream) {
    const float* xa = (const float*)d_in[0];
    const int*   ea = (const int*)d_in[1];
    const float* xp = (const float*)d_in[2];
    const int*   ep = (const int*)d_in[3];
    const float* xn = (const float*)d_in[4];
    const int*   en = (const int*)d_in[5];
    const float* W11 = (const float*)d_in[6];
    const float* b11 = (const float*)d_in[7];
    const float* W12 = (const float*)d_in[8];
    const float* b12 = (const float*)d_in[9];
    const float* W21 = (const float*)d_in[10];
    const float* b21 = (const float*)d_in[11];
    const float* W22 = (const float*)d_in[12];
    const float* b22 = (const float*)d_in[13];
    const float* Wf  = (const float*)d_in[14];
    const float* bf  = (const float*)d_in[15];

    float*  ws    = (float*)d_ws;
    uint32* X1    = (uint32*)(ws + X1_OFF);
    uint32* H2    = (uint32*)(ws + H2_OFF);
    int*    col   = (int*)(ws + COL_OFF);
    int*    rp    = (int*)(ws + RP_OFF);
    float*  gsum  = ws + GSUM_OFF;
    float*  ts    = ws + TS_OFF;
    float*  UV    = ws + UV_OFF;
    uint32* gh    = (uint32*)(ws + GH_OFF);
    uint32* offsP = (uint32*)(ws + OFFS_OFF);
    int*    tot   = (int*)(ws + TOT_OFF);
    uint32* W21p  = (uint32*)(ws + W21P_OFF);
    uint32* W22p  = (uint32*)(ws + W22P_OFF);
    float*  out   = (float*)d_out;

    prep_kernel<<<1, 128, 0, stream>>>(W11, b11, W12, b12, W21, W22, ts, UV, W21p, W22p, gsum);
    hist_kernel<<<dim3(BPG, 3), 256, 0, stream>>>(ea, ep, en, gh);
    colscan_kernel<<<dim3((NPAIR + 255) / 256, 3), 256, 0, stream>>>(gh, offsP, tot);
    scan_kernel<<<3, 256, 0, stream>>>(tot, rp);
    fill_kernel<<<dim3(BPG, 3), 256, 0, stream>>>(ea, ep, en, rp, offsP, col);
    l1_kernel<<<dim3(NB / 4, 3), 256, 0, stream>>>(xa, xp, xn, rp, col, ts, UV, X1);
    // 3 balanced phases x 2 tasks x 4 XCDs; per-XCD working set 2.56MB (L2-resident)
    gather2_kernel<<<10000, 256, 0, stream>>>(rp, col, X1, H2, 0, 0, 1, 0);
    gather2_kernel<<<10000, 256, 0, stream>>>(rp, col, X1, H2, 2, 0, 2, 1);
    gather2_kernel<<<10000, 256, 0, stream>>>(rp, col, X1, H2, 0, 1, 1, 1);
    mlp2_kernel<<<dim3(NBLK64, 3), 256, 0, stream>>>(H2, W21p, b21, W22p, b22, gsum);
    final_kernel<<<1, 384, 0, stream>>>(gsum, Wf, bf, out);
}

// Round 8
// 260.949 us; speedup vs baseline: 1.5016x; 1.0863x over previous
//
#include <hip/hip_runtime.h>

#define N_NODES 20000
#define N_EDGES 600000
#define HID 128
#define NB N_NODES
#define NBLK64 313                  // ceil(20000/64)
#define BPG 160                     // CSR-build blocks per graph
#define CHUNK (N_EDGES / BPG)       // 3750
#define NPAIR (NB / 2)              // 10000
#define NQUAD (NB / 4)              // 5000 (u8-packed histogram words)

typedef unsigned int uint32;
typedef __attribute__((ext_vector_type(8))) short bf16x8v;   // 8 bf16 in 4 VGPRs
typedef __attribute__((ext_vector_type(4))) float f32x4;

// ---------------- workspace layout (4-byte words) ----------------
// CSR-build scratch (gh/offsP/tot) is DEAD before l1/gather2 write X1/H2,
// so it aliases the X1/H2 region (strictly stream-ordered).
#define GH_OFF   0                  // 3*160*5000 u32 (4x u8 counts)   [aliases X1]
#define OFFS_OFF 2400000            // 3*160*10000 u32 (2x u16 prefix) [aliases X1/H2]
#define TOT_OFF  7200000            // 3*20000 int                     [aliases H2]
#define X1_OFF   0                  // x1 bf16-packed: 3*20000*64
#define H2_OFF   3840000            // h2 bf16-packed: 3*20000*64
#define COL_OFF  7680000            // 3*600000 int
#define RP_OFF   9480000            // 3*20001 int
#define GSUM_OFF 9540008            // 3*128 f32
#define TS_OFF   9540392            // 128 f32 sorted breakpoints
#define UV_OFF   9540520            // 129 x (U[128],V[128]) f32 = 33024
#define W21P_OFF 9573544            // 128*128 bf16 frag-packed = 8192 words
#define W22P_OFF 9581736            // 8192 words
#define ORD_OFF  9589928            // 128 int (breakpoint order)
// end 9,590,056 words = 38.4 MB

static __device__ inline unsigned short f2bf(float f) {
    uint32 u = __float_as_uint(f);
    return (unsigned short)((u + 0x7fffu + ((u >> 16) & 1u)) >> 16);
}
static __device__ inline float bf2f(uint32 lo16) {
    return __uint_as_float(lo16 << 16);
}
static __device__ inline uint32 pack2(float a, float b) {
    return (uint32)f2bf(a) | ((uint32)f2bf(b) << 16);
}

// ---- prep stage 1: breakpoints, sort order, zero gsum (tiny) ----
__launch_bounds__(128)
__global__ void prep_sort_kernel(const float* __restrict__ W11, const float* __restrict__ b11,
                                 float* __restrict__ ts, int* __restrict__ ord,
                                 float* __restrict__ gsum) {
    __shared__ float tsh[128];
    int tid = threadIdx.x;   // 128
    float w = W11[tid], b = b11[tid];
    float t = (w != 0.0f) ? (-b / w) : 3.0e38f;
    tsh[tid] = t;
    __syncthreads();
    int rank = 0;
    for (int j = 0; j < 128; ++j) {
        float tj = tsh[j];
        if (tj < t || (tj == t && j < tid)) ++rank;
    }
    ts[rank] = t;
    ord[rank] = tid;
    gsum[tid] = 0.0f; gsum[128 + tid] = 0.0f; gsum[256 + tid] = 0.0f;
}

// ---- prep stage 2 (parallel): UV tables (blocks 0-7) + frag-pack (blocks 8-15) ----
// x1[node] = relu(s*U[p] + V[p]), p = #breakpoints < s. UV[p] built by prefix
// over rank-1 deltas, all staged in LDS (same FP order as the serial version).
__launch_bounds__(256)
__global__ void prep2_kernel(const float* __restrict__ W11, const float* __restrict__ b11,
                             const float* __restrict__ W12, const float* __restrict__ b12,
                             const float* __restrict__ W21, const float* __restrict__ W22,
                             const int* __restrict__ ord,
                             float* __restrict__ UV,
                             uint32* __restrict__ W21p, uint32* __restrict__ W22p) {
    int blk = blockIdx.x, tid = threadIdx.x;
    if (blk < 8) {
        __shared__ float w12s[128][16];   // 8 KB: W12[:, c0:c0+16]
        __shared__ float du[128][16];     // 8 KB: u-delta of pattern j+1
        __shared__ float dv[128][16];     // 8 KB
        __shared__ float wsh[128], bsh[128];
        __shared__ int osh[128];
        int c0 = blk * 16;
        if (tid < 128) { wsh[tid] = W11[tid]; bsh[tid] = b11[tid]; osh[tid] = ord[tid]; }
        {
            int r0 = tid >> 4, c = tid & 15;
            for (int r = r0; r < 128; r += 16)
                w12s[r][c] = W12[r * HID + c0 + c];
        }
        __syncthreads();
        for (int idx = tid; idx < 2048; idx += 256) {
            int j = idx >> 4, c = idx & 15;
            int k = osh[j];
            float wk = wsh[k], bk = bsh[k];
            float w12 = w12s[k][c];
            float s = (wk > 0.f) ? 1.f : ((wk < 0.f) ? -1.f : 0.f);
            du[j][c] = s * wk * w12;
            dv[j][c] = s * bk * w12;
        }
        __syncthreads();
        if (tid < 32) {
            int c = tid & 15;
            if (tid < 16) {           // u chain for column c0+c
                float cur = 0.f;
                for (int k = 0; k < 128; ++k) {
                    float wk = wsh[k];
                    if (wk < 0.f) cur += wk * w12s[k][c];
                }
                UV[c0 + c] = cur;
                for (int j = 0; j < 128; ++j) {
                    cur += du[j][c];
                    UV[(j + 1) * 256 + c0 + c] = cur;
                }
            } else {                  // v chain
                float cur = b12[c0 + c];
                for (int k = 0; k < 128; ++k) {
                    float wk = wsh[k];
                    if (wk < 0.f)                       cur += bsh[k] * w12s[k][c];
                    else if (wk == 0.f && bsh[k] > 0.f) cur += bsh[k] * w12s[k][c];
                }
                UV[128 + c0 + c] = cur;
                for (int j = 0; j < 128; ++j) {
                    cur += dv[j][c];
                    UV[(j + 1) * 256 + 128 + c0 + c] = cur;
                }
            }
        }
    } else {
        // frag-pack W21/W22 -> bf16 MFMA B-frags; one thread per (tt,c,l)
        int idx = (blk - 8) * 256 + tid;      // 0..2047
        int tt = idx >> 9, c = (idx >> 6) & 7, l = idx & 63;
        int kbase = tt * 32 + (l >> 4) * 8;
        int colv = c * 16 + (l & 15);
#pragma unroll
        for (int jw = 0; jw < 4; ++jw) {
            float f0 = W21[(kbase + 2 * jw) * HID + colv];
            float f1 = W21[(kbase + 2 * jw + 1) * HID + colv];
            W21p[idx * 4 + jw] = pack2(f0, f1);
            f0 = W22[(kbase + 2 * jw) * HID + colv];
            f1 = W22[(kbase + 2 * jw + 1) * HID + colv];
            W22p[idx * 4 + jw] = pack2(f0, f1);
        }
    }
}

// ---- CSR phase A: per-block LDS histogram, u8-packed (20KB), 512 thr ----
__launch_bounds__(512)
__global__ void hist_kernel(const int* __restrict__ ea, const int* __restrict__ ep,
                            const int* __restrict__ en, uint32* __restrict__ gh) {
    __shared__ uint32 h[NQUAD];     // 20 KB
    int g = blockIdx.y, blk = blockIdx.x, tid = threadIdx.x;
    const int* e = (g == 0) ? ea : (g == 1) ? ep : en;
    for (int i = tid; i < NQUAD; i += 512) h[i] = 0;
    __syncthreads();
    int base = blk * CHUNK;
    for (int i = tid; i < CHUNK; i += 512) {
        int dst = e[N_EDGES + base + i];
        atomicAdd(&h[dst >> 2], 1u << ((dst & 3) * 8));   // counts << 256 per chunk
    }
    __syncthreads();
    uint32* out = gh + ((size_t)g * BPG + blk) * NQUAD;
    for (int i = tid; i < NQUAD; i += 512) out[i] = h[i];
}

// ---- phase B1: per-(block,pair) u16 prefixes + per-bin totals ----
__launch_bounds__(256)
__global__ void colscan_kernel(const uint32* __restrict__ gh, uint32* __restrict__ offsP,
                               int* __restrict__ tot) {
    int g = blockIdx.y;
    int p = blockIdx.x * 256 + threadIdx.x;   // pair index (nodes 2p, 2p+1)
    if (p >= NPAIR) return;
    const uint32* ghg = gh + (size_t)g * BPG * NQUAD;
    uint32* og = offsP + (size_t)g * BPG * NPAIR;
    int sh = (p & 1) * 16;                     // byte offset of node 2p in its word
    uint32 runLo = 0, runHi = 0;
    for (int k = 0; k < BPG; ++k) {
        uint32 w = ghg[(size_t)k * NQUAD + (p >> 1)] >> sh;
        og[(size_t)k * NPAIR + p] = runLo | (runHi << 16);
        runLo += w & 0xffu;
        runHi += (w >> 8) & 0xffu;
    }
    tot[g * NB + 2 * p]     = (int)runLo;
    tot[g * NB + 2 * p + 1] = (int)runHi;
}

// ---- phase B2: exclusive scan of totals -> row_ptr ----
__global__ void scan_kernel(const int* __restrict__ tot, int* __restrict__ rp) {
    int g = blockIdx.x;
    int tid = threadIdx.x;                 // 256
    const int CH = (NB + 255) / 256;       // 79
    __shared__ int partial[256];
    int begin = tid * CH; if (begin > NB) begin = NB;
    int end = begin + CH; if (end > NB) end = NB;
    int s = 0;
    for (int i = begin; i < end; ++i) s += tot[g * NB + i];
    partial[tid] = s;
    __syncthreads();
    if (tid == 0) {
        int run = 0;
        for (int i = 0; i < 256; ++i) { int t = partial[i]; partial[i] = run; run += t; }
    }
    __syncthreads();
    int run = partial[tid];
    for (int i = begin; i < end; ++i) {
        rp[g * (NB + 1) + i] = run;
        run += tot[g * NB + i];
    }
    if (tid == 255) rp[g * (NB + 1) + NB] = run;
}

// ---- phase C: fill col[] via u8 LDS rank counters, 512 thr ----
__launch_bounds__(512)
__global__ void fill_kernel(const int* __restrict__ ea, const int* __restrict__ ep,
                            const int* __restrict__ en, const int* __restrict__ rp,
                            const uint32* __restrict__ offsP, int* __restrict__ col) {
    __shared__ uint32 h[NQUAD];     // 20 KB
    int g = blockIdx.y, blk = blockIdx.x, tid = threadIdx.x;
    const int* e = (g == 0) ? ea : (g == 1) ? ep : en;
    for (int i = tid; i < NQUAD; i += 512) h[i] = 0;
    __syncthreads();
    int base = blk * CHUNK;
    const int* rpg = rp + g * (NB + 1);
    const uint32* og = offsP + ((size_t)g * BPG + blk) * NPAIR;
    int* colg = col + (size_t)g * N_EDGES;
    for (int i = tid; i < CHUNK; i += 512) {
        int src = e[base + i];
        int dst = e[N_EDGES + base + i];
        uint32 old = atomicAdd(&h[dst >> 2], 1u << ((dst & 3) * 8));
        int rank = (int)((old >> ((dst & 3) * 8)) & 0xffu);
        int offs = (int)((og[dst >> 1] >> ((dst & 1) * 16)) & 0xffffu);
        colg[rpg[dst] + offs + rank] = src;
    }
}

// ---- L1: scalar gather + pattern-table MLP1 -> x1 (bf16). wave per node ----
__launch_bounds__(256)
__global__ void l1_kernel(const float* __restrict__ xa, const float* __restrict__ xp,
                          const float* __restrict__ xn,
                          const int* __restrict__ rp, const int* __restrict__ col,
                          const float* __restrict__ ts, const float* __restrict__ UV,
                          uint32* __restrict__ X1) {
    __shared__ float tsh[128];
    int tid = threadIdx.x;
    if (tid < 128) tsh[tid] = ts[tid];
    __syncthreads();
    int g = blockIdx.y;
    const float* x = (g == 0) ? xa : (g == 1) ? xp : xn;
    int node = blockIdx.x * 4 + (tid >> 6);
    int lane = tid & 63;
    const int* rpg = rp + g * (NB + 1);
    const int* clg = col + (size_t)g * N_EDGES;
    int beg = rpg[node], end = rpg[node + 1];
    float s = 0.0f;
    for (int j = beg + lane; j < end; j += 64) s += x[clg[j]];
#pragma unroll
    for (int off = 32; off > 0; off >>= 1) s += __shfl_down(s, off);
    s = __shfl(s, 0);
    s += x[node];
    int lo = 0, hi = 128;
    while (lo < hi) { int mid = (lo + hi) >> 1; if (tsh[mid] < s) lo = mid + 1; else hi = mid; }
    const float* Up = UV + (size_t)lo * 256;
    float2 u = *(const float2*)&Up[lane * 2];
    float2 v = *(const float2*)&Up[128 + lane * 2];
    float r0 = fmaxf(fmaf(s, u.x, v.x), 0.0f);
    float r1 = fmaxf(fmaf(s, u.y, v.y), 0.0f);
    X1[(size_t)(g * NB + node) * 64 + lane] = pack2(r0, r1);
}

// ---- L2 aggregation, high-ILP half-row gather ----
// XCDs 0-3 run (gA,hA), XCDs 4-7 run (gB,hB). Lane owns 8B of a 128B half-row
// (16 lanes/edge, 4 edges per wave-instr, 16 edges per main iter).
__launch_bounds__(256)
__global__ void gather2_kernel(const int* __restrict__ rp, const int* __restrict__ col,
                               const uint32* __restrict__ X1, uint32* __restrict__ H2,
                               int gA, int hA, int gB, int hB) {
    int b = blockIdx.x;
    int xcd = b & 7, slot = b >> 3;
    int g = (xcd >> 2) ? gB : gA;
    int h = (xcd >> 2) ? hB : hA;
    int nb = slot * 4 + (xcd & 3);            // 0..4999
    int node = nb * 4 + (threadIdx.x >> 6);
    int lane = threadIdx.x & 63;
    int sub = lane >> 4;                       // edge slot 0..3
    int w = lane & 15;                         // uint2 index within 128B half
    const int* rpg = rp + g * (NB + 1);
    const int* clg = col + (size_t)g * N_EDGES;
    int beg = rpg[node], end = rpg[node + 1];
    const uint32* Bg = X1 + (size_t)g * NB * 64 + h * 32;
    float a0 = 0.f, a1 = 0.f, a2 = 0.f, a3 = 0.f;
    int j = beg;
    for (; j + 16 <= end; j += 16) {           // 16 edges, 4 loads in flight/lane
        int jb = j + sub * 4;
        int c0 = clg[jb], c1 = clg[jb + 1], c2 = clg[jb + 2], c3 = clg[jb + 3];
        uint2 v0 = *(const uint2*)&Bg[(size_t)c0 * 64 + w * 2];
        uint2 v1 = *(const uint2*)&Bg[(size_t)c1 * 64 + w * 2];
        uint2 v2 = *(const uint2*)&Bg[(size_t)c2 * 64 + w * 2];
        uint2 v3 = *(const uint2*)&Bg[(size_t)c3 * 64 + w * 2];
        a0 += bf2f(v0.x & 0xffffu) + bf2f(v1.x & 0xffffu) + bf2f(v2.x & 0xffffu) + bf2f(v3.x & 0xffffu);
        a1 += bf2f(v0.x >> 16)     + bf2f(v1.x >> 16)     + bf2f(v2.x >> 16)     + bf2f(v3.x >> 16);
        a2 += bf2f(v0.y & 0xffffu) + bf2f(v1.y & 0xffffu) + bf2f(v2.y & 0xffffu) + bf2f(v3.y & 0xffffu);
        a3 += bf2f(v0.y >> 16)     + bf2f(v1.y >> 16)     + bf2f(v2.y >> 16)     + bf2f(v3.y >> 16);
    }
    for (; j + 4 <= end; j += 4) {             // 4 edges per iter
        int c0 = clg[j + sub];
        uint2 v0 = *(const uint2*)&Bg[(size_t)c0 * 64 + w * 2];
        a0 += bf2f(v0.x & 0xffffu); a1 += bf2f(v0.x >> 16);
        a2 += bf2f(v0.y & 0xffffu); a3 += bf2f(v0.y >> 16);
    }
    if (j + sub < end) {                       // masked tail (<4 edges)
        int c0 = clg[j + sub];
        uint2 v0 = *(const uint2*)&Bg[(size_t)c0 * 64 + w * 2];
        a0 += bf2f(v0.x & 0xffffu); a1 += bf2f(v0.x >> 16);
        a2 += bf2f(v0.y & 0xffffu); a3 += bf2f(v0.y >> 16);
    }
    a0 += __shfl_xor(a0, 16); a0 += __shfl_xor(a0, 32);
    a1 += __shfl_xor(a1, 16); a1 += __shfl_xor(a1, 32);
    a2 += __shfl_xor(a2, 16); a2 += __shfl_xor(a2, 32);
    a3 += __shfl_xor(a3, 16); a3 += __shfl_xor(a3, 32);
    if (sub == 0) {
        uint2 sv = *(const uint2*)&Bg[(size_t)node * 64 + w * 2];
        a0 += bf2f(sv.x & 0xffffu); a1 += bf2f(sv.x >> 16);
        a2 += bf2f(sv.y & 0xffffu); a3 += bf2f(sv.y >> 16);
        uint2 o; o.x = pack2(a0, a1); o.y = pack2(a2, a3);
        *(uint2*)&H2[(size_t)(g * NB + node) * 64 + h * 32 + w * 2] = o;
    }
}

// ---- MFMA MLP2: x2 = relu(relu(h2@W21+b21)@W22+b22), pool-only ----
__launch_bounds__(256)
__global__ void mlp2_kernel(const uint32* __restrict__ H2,
                            const uint32* __restrict__ W21p, const float* __restrict__ b21,
                            const uint32* __restrict__ W22p, const float* __restrict__ b22,
                            float* __restrict__ gsum) {
    __shared__ uint32 tl[64 * 64];      // t tile, bf16, XOR-swizzled rows of 256B
    __shared__ float psum[HID];
    int g = blockIdx.y;
    int base = blockIdx.x * 64;
    int nvalid = NB - base; if (nvalid > 64) nvalid = 64;
    int tid = threadIdx.x;
    int wave = tid >> 6, l = tid & 63;
    int lq = l >> 4, lr = l & 15;
    if (tid < HID) psum[tid] = 0.0f;
    __syncthreads();

    f32x4 acc[8];
#pragma unroll
    for (int c = 0; c < 8; ++c) acc[c] = (f32x4){0.f, 0.f, 0.f, 0.f};
    int arow = wave * 16 + lr;
    int arowc = (arow < nvalid) ? arow : 0;
    const uint32* h2row = H2 + ((size_t)g * NB + base + arowc) * 64;
#pragma unroll
    for (int t = 0; t < 4; ++t) {
        uint4 av = *(const uint4*)&h2row[t * 16 + lq * 4];
        bf16x8v af = __builtin_bit_cast(bf16x8v, av);
#pragma unroll
        for (int c = 0; c < 8; ++c) {
            uint4 bv = *(const uint4*)&W21p[((t * 8 + c) * 64 + l) * 4];
            acc[c] = __builtin_amdgcn_mfma_f32_16x16x32_bf16(
                af, __builtin_bit_cast(bf16x8v, bv), acc[c], 0, 0, 0);
        }
    }
    unsigned short* tls = (unsigned short*)tl;
#pragma unroll
    for (int c = 0; c < 8; ++c) {
        int colv = c * 16 + lr;
        float bb = b21[colv];
#pragma unroll
        for (int q = 0; q < 4; ++q) {
            int row = wave * 16 + lq * 4 + q;
            float v = fmaxf(acc[c][q] + bb, 0.0f);
            int byte = row * 256 + ((colv * 2) ^ ((row & 7) << 4));
            tls[byte >> 1] = f2bf(v);
        }
    }
    f32x4 acc2[8];
#pragma unroll
    for (int c = 0; c < 8; ++c) acc2[c] = (f32x4){0.f, 0.f, 0.f, 0.f};
#pragma unroll
    for (int t = 0; t < 4; ++t) {
        int rbyte = arow * 256 + (((t * 64 + lq * 16)) ^ ((arow & 7) << 4));
        uint4 av = *(const uint4*)((const char*)tl + rbyte);
        bf16x8v af = __builtin_bit_cast(bf16x8v, av);
#pragma unroll
        for (int c = 0; c < 8; ++c) {
            uint4 bv = *(const uint4*)&W22p[((t * 8 + c) * 64 + l) * 4];
            acc2[c] = __builtin_amdgcn_mfma_f32_16x16x32_bf16(
                af, __builtin_bit_cast(bf16x8v, bv), acc2[c], 0, 0, 0);
        }
    }
#pragma unroll
    for (int c = 0; c < 8; ++c) {
        float bb = b22[c * 16 + lr];
        float s = 0.0f;
#pragma unroll
        for (int q = 0; q < 4; ++q) {
            int row = wave * 16 + lq * 4 + q;
            float v = fmaxf(acc2[c][q] + bb, 0.0f);
            s += (row < nvalid) ? v : 0.0f;
        }
        s += __shfl_xor(s, 16);
        s += __shfl_xor(s, 32);
        if (lq == 0) atomicAdd(&psum[c * 16 + lr], s);
    }
    __syncthreads();
    if (tid < HID) atomicAdd(&gsum[g * HID + tid], psum[tid]);
}

// ---- triplet head ----
__global__ void final_kernel(const float* __restrict__ gsum, const float* __restrict__ Wf,
                             const float* __restrict__ bf, float* __restrict__ out) {
    int tid = threadIdx.x;  // 384
    int g = tid >> 7;
    int o = tid & 127;
    float acc = bf[o];
    for (int k = 0; k < HID; ++k)
        acc += gsum[g * HID + k] * Wf[k * HID + o];
    out[g * HID + o] = acc;
}

extern "C" void kernel_launch(void* const* d_in, const int* in_sizes, int n_in,
                              void* d_out, int out_size, void* d_ws, size_t ws_size,
                              hipStream_t stream) {
    const float* xa = (const float*)d_in[0];
    const int*   ea = (const int*)d_in[1];
    const float* xp = (const float*)d_in[2];
    const int*   ep = (const int*)d_in[3];
    const float* xn = (const float*)d_in[4];
    const int*   en = (const int*)d_in[5];
    const float* W11 = (const float*)d_in[6];
    const float* b11 = (const float*)d_in[7];
    const float* W12 = (const float*)d_in[8];
    const float* b12 = (const float*)d_in[9];
    const float* W21 = (const float*)d_in[10];
    const float* b21 = (const float*)d_in[11];
    const float* W22 = (const float*)d_in[12];
    const float* b22 = (const float*)d_in[13];
    const float* Wf  = (const float*)d_in[14];
    const float* bf  = (const float*)d_in[15];

    float*  ws    = (float*)d_ws;
    uint32* X1    = (uint32*)(ws + X1_OFF);
    uint32* H2    = (uint32*)(ws + H2_OFF);
    int*    col   = (int*)(ws + COL_OFF);
    int*    rp    = (int*)(ws + RP_OFF);
    float*  gsum  = ws + GSUM_OFF;
    float*  ts    = ws + TS_OFF;
    float*  UV    = ws + UV_OFF;
    uint32* gh    = (uint32*)(ws + GH_OFF);
    uint32* offsP = (uint32*)(ws + OFFS_OFF);
    int*    tot   = (int*)(ws + TOT_OFF);
    uint32* W21p  = (uint32*)(ws + W21P_OFF);
    uint32* W22p  = (uint32*)(ws + W22P_OFF);
    int*    ord   = (int*)(ws + ORD_OFF);
    float*  out   = (float*)d_out;

    prep_sort_kernel<<<1, 128, 0, stream>>>(W11, b11, ts, ord, gsum);
    prep2_kernel<<<16, 256, 0, stream>>>(W11, b11, W12, b12, W21, W22, ord, UV, W21p, W22p);
    hist_kernel<<<dim3(BPG, 3), 512, 0, stream>>>(ea, ep, en, gh);
    colscan_kernel<<<dim3((NPAIR + 255) / 256, 3), 256, 0, stream>>>(gh, offsP, tot);
    scan_kernel<<<3, 256, 0, stream>>>(tot, rp);
    fill_kernel<<<dim3(BPG, 3), 512, 0, stream>>>(ea, ep, en, rp, offsP, col);
    l1_kernel<<<dim3(NB / 4, 3), 256, 0, stream>>>(xa, xp, xn, rp, col, ts, UV, X1);
    // 3 balanced phases x 2 tasks x 4 XCDs; per-XCD working set 2.56MB (L2-resident)
    gather2_kernel<<<10000, 256, 0, stream>>>(rp, col, X1, H2, 0, 0, 1, 0);
    gather2_kernel<<<10000, 256, 0, stream>>>(rp, col, X1, H2, 2, 0, 2, 1);
    gather2_kernel<<<10000, 256, 0, stream>>>(rp, col, X1, H2, 0, 1, 1, 1);
    mlp2_kernel<<<dim3(NBLK64, 3), 256, 0, stream>>>(H2, W21p, b21, W22p, b22, gsum);
    final_kernel<<<1, 384, 0, stream>>>(gsum, Wf, bf, out);
}

// Round 9
// 200.563 us; speedup vs baseline: 1.9537x; 1.3011x over previous
//
#include <hip/hip_runtime.h>

#define N_NODES 20000
#define N_EDGES 600000
#define HID 128
#define NB N_NODES
#define NBLK64 313                  // ceil(20000/64)
#define BPG 160                     // partition blocks per graph
#define CHUNK (N_EDGES / BPG)       // 3750
#define NBUCK 157                   // ceil(20000/128) dst-buckets
#define BSH 7                       // bucket = dst >> 7

typedef unsigned int uint32;
typedef __attribute__((ext_vector_type(8))) short bf16x8v;   // 8 bf16 in 4 VGPRs
typedef __attribute__((ext_vector_type(4))) float f32x4;

// ---------------- workspace layout (4-byte words) ----------------
// Bucket-sort scratch (P/bcnt/bbase) is DEAD before l1 writes X1 (stream-ordered).
#define P_OFF     0                 // 3*600000 u32 packed (src | (dst&127)<<16)  [aliases X1]
#define BCNT_OFF  1800000           // 3*160*157 u32                              [aliases X1]
#define BBASE_OFF 1875360           // 3*158 u32                                  [aliases X1]
#define X1_OFF    0                 // x1 bf16-packed: 3*20000*64
#define H2_OFF    3840000           // h2 bf16-packed: 3*20000*64
#define COL_OFF   7680000           // 3*600000 int (src ids)
#define RP_OFF    9480000           // 3*20001 int
#define GSUM_OFF  9540008           // 3*128 f32
#define TS_OFF    9540392           // 128 f32 sorted breakpoints
#define UV_OFF    9540520           // 129 x (U[128],V[128]) f32 = 33024
#define W21P_OFF  9573544           // 128*128 bf16 frag-packed = 8192 words
#define W22P_OFF  9581736           // 8192 words
#define ORD_OFF   9589928           // 128 int (breakpoint order)
// end 9,590,056 words = 38.4 MB

static __device__ inline unsigned short f2bf(float f) {
    uint32 u = __float_as_uint(f);
    return (unsigned short)((u + 0x7fffu + ((u >> 16) & 1u)) >> 16);
}
static __device__ inline float bf2f(uint32 lo16) {
    return __uint_as_float(lo16 << 16);
}
static __device__ inline uint32 pack2(float a, float b) {
    return (uint32)f2bf(a) | ((uint32)f2bf(b) << 16);
}

// ---- prep stage 1: breakpoints, sort order, zero gsum (tiny) ----
__launch_bounds__(128)
__global__ void prep_sort_kernel(const float* __restrict__ W11, const float* __restrict__ b11,
                                 float* __restrict__ ts, int* __restrict__ ord,
                                 float* __restrict__ gsum) {
    __shared__ float tsh[128];
    int tid = threadIdx.x;   // 128
    float w = W11[tid], b = b11[tid];
    float t = (w != 0.0f) ? (-b / w) : 3.0e38f;
    tsh[tid] = t;
    __syncthreads();
    int rank = 0;
    for (int j = 0; j < 128; ++j) {
        float tj = tsh[j];
        if (tj < t || (tj == t && j < tid)) ++rank;
    }
    ts[rank] = t;
    ord[rank] = tid;
    gsum[tid] = 0.0f; gsum[128 + tid] = 0.0f; gsum[256 + tid] = 0.0f;
}

// ---- prep stage 2 (parallel): UV tables (blocks 0-7) + frag-pack (blocks 8-15) ----
__launch_bounds__(256)
__global__ void prep2_kernel(const float* __restrict__ W11, const float* __restrict__ b11,
                             const float* __restrict__ W12, const float* __restrict__ b12,
                             const float* __restrict__ W21, const float* __restrict__ W22,
                             const int* __restrict__ ord,
                             float* __restrict__ UV,
                             uint32* __restrict__ W21p, uint32* __restrict__ W22p) {
    int blk = blockIdx.x, tid = threadIdx.x;
    if (blk < 8) {
        __shared__ float w12s[128][16];
        __shared__ float du[128][16];
        __shared__ float dv[128][16];
        __shared__ float wsh[128], bsh[128];
        __shared__ int osh[128];
        int c0 = blk * 16;
        if (tid < 128) { wsh[tid] = W11[tid]; bsh[tid] = b11[tid]; osh[tid] = ord[tid]; }
        {
            int r0 = tid >> 4, c = tid & 15;
            for (int r = r0; r < 128; r += 16)
                w12s[r][c] = W12[r * HID + c0 + c];
        }
        __syncthreads();
        for (int idx = tid; idx < 2048; idx += 256) {
            int j = idx >> 4, c = idx & 15;
            int k = osh[j];
            float wk = wsh[k], bk = bsh[k];
            float w12 = w12s[k][c];
            float s = (wk > 0.f) ? 1.f : ((wk < 0.f) ? -1.f : 0.f);
            du[j][c] = s * wk * w12;
            dv[j][c] = s * bk * w12;
        }
        __syncthreads();
        if (tid < 32) {
            int c = tid & 15;
            if (tid < 16) {           // u chain for column c0+c
                float cur = 0.f;
                for (int k = 0; k < 128; ++k) {
                    float wk = wsh[k];
                    if (wk < 0.f) cur += wk * w12s[k][c];
                }
                UV[c0 + c] = cur;
                for (int j = 0; j < 128; ++j) {
                    cur += du[j][c];
                    UV[(j + 1) * 256 + c0 + c] = cur;
                }
            } else {                  // v chain
                float cur = b12[c0 + c];
                for (int k = 0; k < 128; ++k) {
                    float wk = wsh[k];
                    if (wk < 0.f)                       cur += bsh[k] * w12s[k][c];
                    else if (wk == 0.f && bsh[k] > 0.f) cur += bsh[k] * w12s[k][c];
                }
                UV[128 + c0 + c] = cur;
                for (int j = 0; j < 128; ++j) {
                    cur += dv[j][c];
                    UV[(j + 1) * 256 + 128 + c0 + c] = cur;
                }
            }
        }
    } else {
        int idx = (blk - 8) * 256 + tid;      // 0..2047
        int tt = idx >> 9, c = (idx >> 6) & 7, l = idx & 63;
        int kbase = tt * 32 + (l >> 4) * 8;
        int colv = c * 16 + (l & 15);
#pragma unroll
        for (int jw = 0; jw < 4; ++jw) {
            float f0 = W21[(kbase + 2 * jw) * HID + colv];
            float f1 = W21[(kbase + 2 * jw + 1) * HID + colv];
            W21p[idx * 4 + jw] = pack2(f0, f1);
            f0 = W22[(kbase + 2 * jw) * HID + colv];
            f1 = W22[(kbase + 2 * jw + 1) * HID + colv];
            W22p[idx * 4 + jw] = pack2(f0, f1);
        }
    }
}

// ---- bucket phase A: per-block 157-bucket histogram ----
__launch_bounds__(512)
__global__ void bhist_kernel(const int* __restrict__ ea, const int* __restrict__ ep,
                             const int* __restrict__ en, uint32* __restrict__ bcnt) {
    __shared__ uint32 c[NBUCK];
    int g = blockIdx.y, blk = blockIdx.x, tid = threadIdx.x;
    const int* e = (g == 0) ? ea : (g == 1) ? ep : en;
    if (tid < NBUCK) c[tid] = 0;
    __syncthreads();
    int base = blk * CHUNK;
    for (int i = tid; i < CHUNK; i += 512)
        atomicAdd(&c[e[N_EDGES + base + i] >> BSH], 1u);
    __syncthreads();
    if (tid < NBUCK) bcnt[((size_t)g * BPG + blk) * NBUCK + tid] = c[tid];
}

// ---- bucket phase B: per-(block,bucket) offsets (in-place) + bucket bases ----
__launch_bounds__(256)
__global__ void bscan_kernel(uint32* __restrict__ bcnt, uint32* __restrict__ bbase) {
    __shared__ uint32 btot[NBUCK];
    int g = blockIdx.x, tid = threadIdx.x;
    if (tid < NBUCK) {
        uint32 run = 0;
        for (int blk = 0; blk < BPG; ++blk) {
            size_t idx = ((size_t)g * BPG + blk) * NBUCK + tid;
            uint32 t = bcnt[idx];
            bcnt[idx] = run;          // per-(block,bucket) prefix within bucket
            run += t;
        }
        btot[tid] = run;
    }
    __syncthreads();
    if (tid == 0) {
        uint32 run = 0;
        for (int k = 0; k < NBUCK; ++k) { bbase[g * 158 + k] = run; run += btot[k]; }
        bbase[g * 158 + NBUCK] = run;   // == N_EDGES
    }
}

// ---- bucket phase C: partition edges into bucket-major P (packed) ----
__launch_bounds__(512)
__global__ void bpart_kernel(const int* __restrict__ ea, const int* __restrict__ ep,
                             const int* __restrict__ en, const uint32* __restrict__ bcnt,
                             const uint32* __restrict__ bbase, uint32* __restrict__ P) {
    __shared__ uint32 cur[NBUCK];
    int g = blockIdx.y, blk = blockIdx.x, tid = threadIdx.x;
    const int* e = (g == 0) ? ea : (g == 1) ? ep : en;
    if (tid < NBUCK)
        cur[tid] = bbase[g * 158 + tid] + bcnt[((size_t)g * BPG + blk) * NBUCK + tid];
    __syncthreads();
    int base = blk * CHUNK;
    uint32* Pg = P + (size_t)g * N_EDGES;
    for (int i = tid; i < CHUNK; i += 512) {
        int src = e[base + i];
        int dst = e[N_EDGES + base + i];
        uint32 pos = atomicAdd(&cur[dst >> BSH], 1u);
        Pg[pos] = (uint32)src | ((uint32)(dst & 127) << 16);
    }
}

// ---- bucket phase D: per-bucket local CSR -> rp + col ----
__launch_bounds__(256)
__global__ void bcsr_kernel(const uint32* __restrict__ bbase, const uint32* __restrict__ P,
                            int* __restrict__ rp, int* __restrict__ col) {
    __shared__ uint32 h[128];
    __shared__ uint32 lscan[128];
    int k = blockIdx.x, g = blockIdx.y, tid = threadIdx.x;
    int beg = (int)bbase[g * 158 + k], end = (int)bbase[g * 158 + k + 1];
    int size = end - beg;
    int n0 = k * 128;
    int cnt_nodes = NB - n0; if (cnt_nodes > 128) cnt_nodes = 128;
    if (tid < 128) h[tid] = 0;
    __syncthreads();
    const uint32* Pg = P + (size_t)g * N_EDGES + beg;
    for (int i = tid; i < size; i += 256)
        atomicAdd(&h[(Pg[i] >> 16) & 127], 1u);
    __syncthreads();
    if (tid == 0) {
        uint32 run = 0;
        for (int d = 0; d < 128; ++d) { lscan[d] = run; run += h[d]; }
    }
    __syncthreads();
    if (tid < cnt_nodes) rp[g * (NB + 1) + n0 + tid] = beg + (int)lscan[tid];
    if (k == NBUCK - 1 && tid == 0) rp[g * (NB + 1) + NB] = end;
    if (tid < 128) h[tid] = lscan[tid];      // repurpose as rank cursors
    __syncthreads();
    int* colg = col + (size_t)g * N_EDGES + beg;
    for (int i = tid; i < size; i += 256) {
        uint32 w = Pg[i];
        uint32 r = atomicAdd(&h[(w >> 16) & 127], 1u);
        colg[r] = (int)(w & 0xffffu);        // scatter within this block's ~15KB window
    }
}

// ---- L1: scalar gather + pattern-table MLP1 -> x1 (bf16). wave per node ----
__launch_bounds__(256)
__global__ void l1_kernel(const float* __restrict__ xa, const float* __restrict__ xp,
                          const float* __restrict__ xn,
                          const int* __restrict__ rp, const int* __restrict__ col,
                          const float* __restrict__ ts, const float* __restrict__ UV,
                          uint32* __restrict__ X1) {
    __shared__ float tsh[128];
    int tid = threadIdx.x;
    if (tid < 128) tsh[tid] = ts[tid];
    __syncthreads();
    int g = blockIdx.y;
    const float* x = (g == 0) ? xa : (g == 1) ? xp : xn;
    int node = blockIdx.x * 4 + (tid >> 6);
    int lane = tid & 63;
    const int* rpg = rp + g * (NB + 1);
    const int* clg = col + (size_t)g * N_EDGES;
    int beg = rpg[node], end = rpg[node + 1];
    float s = 0.0f;
    for (int j = beg + lane; j < end; j += 64) s += x[clg[j]];
#pragma unroll
    for (int off = 32; off > 0; off >>= 1) s += __shfl_down(s, off);
    s = __shfl(s, 0);
    s += x[node];
    int lo = 0, hi = 128;
    while (lo < hi) { int mid = (lo + hi) >> 1; if (tsh[mid] < s) lo = mid + 1; else hi = mid; }
    const float* Up = UV + (size_t)lo * 256;
    float2 u = *(const float2*)&Up[lane * 2];
    float2 v = *(const float2*)&Up[128 + lane * 2];
    float r0 = fmaxf(fmaf(s, u.x, v.x), 0.0f);
    float r1 = fmaxf(fmaf(s, u.y, v.y), 0.0f);
    X1[(size_t)(g * NB + node) * 64 + lane] = pack2(r0, r1);
}

// ---- L2 aggregation, high-ILP half-row gather ----
__launch_bounds__(256)
__global__ void gather2_kernel(const int* __restrict__ rp, const int* __restrict__ col,
                               const uint32* __restrict__ X1, uint32* __restrict__ H2,
                               int gA, int hA, int gB, int hB) {
    int b = blockIdx.x;
    int xcd = b & 7, slot = b >> 3;
    int g = (xcd >> 2) ? gB : gA;
    int h = (xcd >> 2) ? hB : hA;
    int nb = slot * 4 + (xcd & 3);            // 0..4999
    int node = nb * 4 + (threadIdx.x >> 6);
    int lane = threadIdx.x & 63;
    int sub = lane >> 4;                       // edge slot 0..3
    int w = lane & 15;                         // uint2 index within 128B half
    const int* rpg = rp + g * (NB + 1);
    const int* clg = col + (size_t)g * N_EDGES;
    int beg = rpg[node], end = rpg[node + 1];
    const uint32* Bg = X1 + (size_t)g * NB * 64 + h * 32;
    float a0 = 0.f, a1 = 0.f, a2 = 0.f, a3 = 0.f;
    int j = beg;
    for (; j + 16 <= end; j += 16) {           // 16 edges, 4 loads in flight/lane
        int jb = j + sub * 4;
        int c0 = clg[jb], c1 = clg[jb + 1], c2 = clg[jb + 2], c3 = clg[jb + 3];
        uint2 v0 = *(const uint2*)&Bg[(size_t)c0 * 64 + w * 2];
        uint2 v1 = *(const uint2*)&Bg[(size_t)c1 * 64 + w * 2];
        uint2 v2 = *(const uint2*)&Bg[(size_t)c2 * 64 + w * 2];
        uint2 v3 = *(const uint2*)&Bg[(size_t)c3 * 64 + w * 2];
        a0 += bf2f(v0.x & 0xffffu) + bf2f(v1.x & 0xffffu) + bf2f(v2.x & 0xffffu) + bf2f(v3.x & 0xffffu);
        a1 += bf2f(v0.x >> 16)     + bf2f(v1.x >> 16)     + bf2f(v2.x >> 16)     + bf2f(v3.x >> 16);
        a2 += bf2f(v0.y & 0xffffu) + bf2f(v1.y & 0xffffu) + bf2f(v2.y & 0xffffu) + bf2f(v3.y & 0xffffu);
        a3 += bf2f(v0.y >> 16)     + bf2f(v1.y >> 16)     + bf2f(v2.y >> 16)     + bf2f(v3.y >> 16);
    }
    for (; j + 4 <= end; j += 4) {             // 4 edges per iter
        int c0 = clg[j + sub];
        uint2 v0 = *(const uint2*)&Bg[(size_t)c0 * 64 + w * 2];
        a0 += bf2f(v0.x & 0xffffu); a1 += bf2f(v0.x >> 16);
        a2 += bf2f(v0.y & 0xffffu); a3 += bf2f(v0.y >> 16);
    }
    if (j + sub < end) {                       // masked tail (<4 edges)
        int c0 = clg[j + sub];
        uint2 v0 = *(const uint2*)&Bg[(size_t)c0 * 64 + w * 2];
        a0 += bf2f(v0.x & 0xffffu); a1 += bf2f(v0.x >> 16);
        a2 += bf2f(v0.y & 0xffffu); a3 += bf2f(v0.y >> 16);
    }
    a0 += __shfl_xor(a0, 16); a0 += __shfl_xor(a0, 32);
    a1 += __shfl_xor(a1, 16); a1 += __shfl_xor(a1, 32);
    a2 += __shfl_xor(a2, 16); a2 += __shfl_xor(a2, 32);
    a3 += __shfl_xor(a3, 16); a3 += __shfl_xor(a3, 32);
    if (sub == 0) {
        uint2 sv = *(const uint2*)&Bg[(size_t)node * 64 + w * 2];
        a0 += bf2f(sv.x & 0xffffu); a1 += bf2f(sv.x >> 16);
        a2 += bf2f(sv.y & 0xffffu); a3 += bf2f(sv.y >> 16);
        uint2 o; o.x = pack2(a0, a1); o.y = pack2(a2, a3);
        *(uint2*)&H2[(size_t)(g * NB + node) * 64 + h * 32 + w * 2] = o;
    }
}

// ---- MFMA MLP2: x2 = relu(relu(h2@W21+b21)@W22+b22), pool-only ----
__launch_bounds__(256)
__global__ void mlp2_kernel(const uint32* __restrict__ H2,
                            const uint32* __restrict__ W21p, const float* __restrict__ b21,
                            const uint32* __restrict__ W22p, const float* __restrict__ b22,
                            float* __restrict__ gsum) {
    __shared__ uint32 tl[64 * 64];      // t tile, bf16, XOR-swizzled rows of 256B
    __shared__ float psum[HID];
    int g = blockIdx.y;
    int base = blockIdx.x * 64;
    int nvalid = NB - base; if (nvalid > 64) nvalid = 64;
    int tid = threadIdx.x;
    int wave = tid >> 6, l = tid & 63;
    int lq = l >> 4, lr = l & 15;
    if (tid < HID) psum[tid] = 0.0f;
    __syncthreads();

    f32x4 acc[8];
#pragma unroll
    for (int c = 0; c < 8; ++c) acc[c] = (f32x4){0.f, 0.f, 0.f, 0.f};
    int arow = wave * 16 + lr;
    int arowc = (arow < nvalid) ? arow : 0;
    const uint32* h2row = H2 + ((size_t)g * NB + base + arowc) * 64;
#pragma unroll
    for (int t = 0; t < 4; ++t) {
        uint4 av = *(const uint4*)&h2row[t * 16 + lq * 4];
        bf16x8v af = __builtin_bit_cast(bf16x8v, av);
#pragma unroll
        for (int c = 0; c < 8; ++c) {
            uint4 bv = *(const uint4*)&W21p[((t * 8 + c) * 64 + l) * 4];
            acc[c] = __builtin_amdgcn_mfma_f32_16x16x32_bf16(
                af, __builtin_bit_cast(bf16x8v, bv), acc[c], 0, 0, 0);
        }
    }
    unsigned short* tls = (unsigned short*)tl;
#pragma unroll
    for (int c = 0; c < 8; ++c) {
        int colv = c * 16 + lr;
        float bb = b21[colv];
#pragma unroll
        for (int q = 0; q < 4; ++q) {
            int row = wave * 16 + lq * 4 + q;
            float v = fmaxf(acc[c][q] + bb, 0.0f);
            int byte = row * 256 + ((colv * 2) ^ ((row & 7) << 4));
            tls[byte >> 1] = f2bf(v);
        }
    }
    f32x4 acc2[8];
#pragma unroll
    for (int c = 0; c < 8; ++c) acc2[c] = (f32x4){0.f, 0.f, 0.f, 0.f};
#pragma unroll
    for (int t = 0; t < 4; ++t) {
        int rbyte = arow * 256 + (((t * 64 + lq * 16)) ^ ((arow & 7) << 4));
        uint4 av = *(const uint4*)((const char*)tl + rbyte);
        bf16x8v af = __builtin_bit_cast(bf16x8v, av);
#pragma unroll
        for (int c = 0; c < 8; ++c) {
            uint4 bv = *(const uint4*)&W22p[((t * 8 + c) * 64 + l) * 4];
            acc2[c] = __builtin_amdgcn_mfma_f32_16x16x32_bf16(
                af, __builtin_bit_cast(bf16x8v, bv), acc2[c], 0, 0, 0);
        }
    }
#pragma unroll
    for (int c = 0; c < 8; ++c) {
        float bb = b22[c * 16 + lr];
        float s = 0.0f;
#pragma unroll
        for (int q = 0; q < 4; ++q) {
            int row = wave * 16 + lq * 4 + q;
            float v = fmaxf(acc2[c][q] + bb, 0.0f);
            s += (row < nvalid) ? v : 0.0f;
        }
        s += __shfl_xor(s, 16);
        s += __shfl_xor(s, 32);
        if (lq == 0) atomicAdd(&psum[c * 16 + lr], s);
    }
    __syncthreads();
    if (tid < HID) atomicAdd(&gsum[g * HID + tid], psum[tid]);
}

// ---- triplet head ----
__global__ void final_kernel(const float* __restrict__ gsum, const float* __restrict__ Wf,
                             const float* __restrict__ bf, float* __restrict__ out) {
    int tid = threadIdx.x;  // 384
    int g = tid >> 7;
    int o = tid & 127;
    float acc = bf[o];
    for (int k = 0; k < HID; ++k)
        acc += gsum[g * HID + k] * Wf[k * HID + o];
    out[g * HID + o] = acc;
}

extern "C" void kernel_launch(void* const* d_in, const int* in_sizes, int n_in,
                              void* d_out, int out_size, void* d_ws, size_t ws_size,
                              hipStream_t stream) {
    const float* xa = (const float*)d_in[0];
    const int*   ea = (const int*)d_in[1];
    const float* xp = (const float*)d_in[2];
    const int*   ep = (const int*)d_in[3];
    const float* xn = (const float*)d_in[4];
    const int*   en = (const int*)d_in[5];
    const float* W11 = (const float*)d_in[6];
    const float* b11 = (const float*)d_in[7];
    const float* W12 = (const float*)d_in[8];
    const float* b12 = (const float*)d_in[9];
    const float* W21 = (const float*)d_in[10];
    const float* b21 = (const float*)d_in[11];
    const float* W22 = (const float*)d_in[12];
    const float* b22 = (const float*)d_in[13];
    const float* Wf  = (const float*)d_in[14];
    const float* bf  = (const float*)d_in[15];

    float*  ws    = (float*)d_ws;
    uint32* X1    = (uint32*)(ws + X1_OFF);
    uint32* H2    = (uint32*)(ws + H2_OFF);
    int*    col   = (int*)(ws + COL_OFF);
    int*    rp    = (int*)(ws + RP_OFF);
    float*  gsum  = ws + GSUM_OFF;
    float*  ts    = ws + TS_OFF;
    float*  UV    = ws + UV_OFF;
    uint32* P     = (uint32*)(ws + P_OFF);
    uint32* bcnt  = (uint32*)(ws + BCNT_OFF);
    uint32* bbase = (uint32*)(ws + BBASE_OFF);
    uint32* W21p  = (uint32*)(ws + W21P_OFF);
    uint32* W22p  = (uint32*)(ws + W22P_OFF);
    int*    ord   = (int*)(ws + ORD_OFF);
    float*  out   = (float*)d_out;

    prep_sort_kernel<<<1, 128, 0, stream>>>(W11, b11, ts, ord, gsum);
    prep2_kernel<<<16, 256, 0, stream>>>(W11, b11, W12, b12, W21, W22, ord, UV, W21p, W22p);
    // bucket-sorted CSR build (no device atomics, write-local scatter)
    bhist_kernel<<<dim3(BPG, 3), 512, 0, stream>>>(ea, ep, en, bcnt);
    bscan_kernel<<<3, 256, 0, stream>>>(bcnt, bbase);
    bpart_kernel<<<dim3(BPG, 3), 512, 0, stream>>>(ea, ep, en, bcnt, bbase, P);
    bcsr_kernel<<<dim3(NBUCK, 3), 256, 0, stream>>>(bbase, P, rp, col);
    // GIN pipeline
    l1_kernel<<<dim3(NB / 4, 3), 256, 0, stream>>>(xa, xp, xn, rp, col, ts, UV, X1);
    gather2_kernel<<<10000, 256, 0, stream>>>(rp, col, X1, H2, 0, 0, 1, 0);
    gather2_kernel<<<10000, 256, 0, stream>>>(rp, col, X1, H2, 2, 0, 2, 1);
    gather2_kernel<<<10000, 256, 0, stream>>>(rp, col, X1, H2, 0, 1, 1, 1);
    mlp2_kernel<<<dim3(NBLK64, 3), 256, 0, stream>>>(H2, W21p, b21, W22p, b22, gsum);
    final_kernel<<<1, 384, 0, stream>>>(gsum, Wf, bf, out);
}

// Round 10
// 180.977 us; speedup vs baseline: 2.1652x; 1.1082x over previous
//
#include <hip/hip_runtime.h>

#define N_NODES 20000
#define N_EDGES 600000
#define HID 128
#define NB N_NODES
#define NBLK64 313                  // ceil(20000/64)
#define BPG 160                     // partition blocks per graph
#define CHUNK (N_EDGES / BPG)       // 3750
#define NBUCK 157                   // ceil(20000/128) dst-buckets
#define BSH 7                       // bucket = dst >> 7

typedef unsigned int uint32;
typedef __attribute__((ext_vector_type(8))) short bf16x8v;   // 8 bf16 in 4 VGPRs
typedef __attribute__((ext_vector_type(4))) float f32x4;

// ---------------- workspace layout (4-byte words), NO aliasing ----------------
#define P_OFF     0                 // 3*600000 u32 packed (src | (dst&127)<<16)
#define BCNT_OFF  1800000           // 3*160*157 u32
#define BBASE_OFF 1875360           // 3*158 u32
#define X1_OFF    1875840           // x1 bf16-packed: 3*20000*64
#define H2_OFF    5715840           // h2 bf16-packed: 3*20000*64
#define COL_OFF   9555840           // 3*600000 int (src ids)
#define RP_OFF    11355840          // 3*20001 int
#define GSUM_OFF  11415848          // 3*128 f32
#define TS_OFF    11416232          // 128 f32 sorted breakpoints
#define UV_OFF    11416360          // 129 x (U[128],V[128]) f32 = 33024
#define W21P_OFF  11449384          // 128*128 bf16 frag-packed = 8192 words
#define W22P_OFF  11457576          // 8192 words
// end 11,465,768 words = 45.9 MB

static __device__ inline unsigned short f2bf(float f) {
    uint32 u = __float_as_uint(f);
    return (unsigned short)((u + 0x7fffu + ((u >> 16) & 1u)) >> 16);
}
static __device__ inline float bf2f(uint32 lo16) {
    return __uint_as_float(lo16 << 16);
}
static __device__ inline uint32 pack2(float a, float b) {
    return (uint32)f2bf(a) | ((uint32)f2bf(b) << 16);
}

// ---- prep (single launch): UV tables (blocks 0-7, local sort) +
//      frag-pack W21/W22 (blocks 8-15) + ts/gsum init ----
__launch_bounds__(256)
__global__ void prep2_kernel(const float* __restrict__ W11, const float* __restrict__ b11,
                             const float* __restrict__ W12, const float* __restrict__ b12,
                             const float* __restrict__ W21, const float* __restrict__ W22,
                             float* __restrict__ ts, float* __restrict__ UV,
                             uint32* __restrict__ W21p, uint32* __restrict__ W22p,
                             float* __restrict__ gsum) {
    int blk = blockIdx.x, tid = threadIdx.x;
    if (blk < 8) {
        __shared__ float w12s[128][16];
        __shared__ float du[128][16];
        __shared__ float dv[128][16];
        __shared__ float wsh[128], bsh[128], tss[128], tsh[128];
        __shared__ int osh[128];
        int c0 = blk * 16;
        if (tid < 128) {
            float w = W11[tid], b = b11[tid];
            wsh[tid] = w; bsh[tid] = b;
            tsh[tid] = (w != 0.0f) ? (-b / w) : 3.0e38f;
        }
        __syncthreads();
        if (tid < 128) {
            float t = tsh[tid];
            int rank = 0;
            for (int j = 0; j < 128; ++j) {
                float tj = tsh[j];
                if (tj < t || (tj == t && j < tid)) ++rank;
            }
            tss[rank] = t; osh[rank] = tid;
        }
        {
            int r0 = tid >> 4, c = tid & 15;
            for (int r = r0; r < 128; r += 16)
                w12s[r][c] = W12[r * HID + c0 + c];
        }
        __syncthreads();
        if (blk == 0 && tid < 128) ts[tid] = tss[tid];
        for (int idx = tid; idx < 2048; idx += 256) {
            int j = idx >> 4, c = idx & 15;
            int k = osh[j];
            float wk = wsh[k], bk = bsh[k];
            float w12 = w12s[k][c];
            float s = (wk > 0.f) ? 1.f : ((wk < 0.f) ? -1.f : 0.f);
            du[j][c] = s * wk * w12;
            dv[j][c] = s * bk * w12;
        }
        __syncthreads();
        if (tid < 32) {
            int c = tid & 15;
            if (tid < 16) {           // u chain for column c0+c
                float cur = 0.f;
                for (int k = 0; k < 128; ++k) {
                    float wk = wsh[k];
                    if (wk < 0.f) cur += wk * w12s[k][c];
                }
                UV[c0 + c] = cur;
                for (int j = 0; j < 128; ++j) {
                    cur += du[j][c];
                    UV[(j + 1) * 256 + c0 + c] = cur;
                }
            } else {                  // v chain
                float cur = b12[c0 + c];
                for (int k = 0; k < 128; ++k) {
                    float wk = wsh[k];
                    if (wk < 0.f)                       cur += bsh[k] * w12s[k][c];
                    else if (wk == 0.f && bsh[k] > 0.f) cur += bsh[k] * w12s[k][c];
                }
                UV[128 + c0 + c] = cur;
                for (int j = 0; j < 128; ++j) {
                    cur += dv[j][c];
                    UV[(j + 1) * 256 + 128 + c0 + c] = cur;
                }
            }
        }
    } else {
        int idx = (blk - 8) * 256 + tid;      // 0..2047
        int tt = idx >> 9, c = (idx >> 6) & 7, l = idx & 63;
        int kbase = tt * 32 + (l >> 4) * 8;
        int colv = c * 16 + (l & 15);
#pragma unroll
        for (int jw = 0; jw < 4; ++jw) {
            float f0 = W21[(kbase + 2 * jw) * HID + colv];
            float f1 = W21[(kbase + 2 * jw + 1) * HID + colv];
            W21p[idx * 4 + jw] = pack2(f0, f1);
            f0 = W22[(kbase + 2 * jw) * HID + colv];
            f1 = W22[(kbase + 2 * jw + 1) * HID + colv];
            W22p[idx * 4 + jw] = pack2(f0, f1);
        }
        if (blk == 8)
            for (int i = tid; i < 384; i += 256) gsum[i] = 0.0f;
    }
}

// ---- bucket phase A: per-block 157-bucket histogram ----
__launch_bounds__(512)
__global__ void bhist_kernel(const int* __restrict__ ea, const int* __restrict__ ep,
                             const int* __restrict__ en, uint32* __restrict__ bcnt) {
    __shared__ uint32 c[NBUCK];
    int g = blockIdx.y, blk = blockIdx.x, tid = threadIdx.x;
    const int* e = (g == 0) ? ea : (g == 1) ? ep : en;
    if (tid < NBUCK) c[tid] = 0;
    __syncthreads();
    int base = blk * CHUNK;
    for (int i = tid; i < CHUNK; i += 512)
        atomicAdd(&c[e[N_EDGES + base + i] >> BSH], 1u);
    __syncthreads();
    if (tid < NBUCK) bcnt[((size_t)g * BPG + blk) * NBUCK + tid] = c[tid];
}

// ---- bucket phase B: per-(block,bucket) offsets (in-place) + bucket bases ----
__launch_bounds__(256)
__global__ void bscan_kernel(uint32* __restrict__ bcnt, uint32* __restrict__ bbase) {
    __shared__ uint32 btot[NBUCK];
    int g = blockIdx.x, tid = threadIdx.x;
    if (tid < NBUCK) {
        uint32 run = 0;
        for (int blk = 0; blk < BPG; ++blk) {
            size_t idx = ((size_t)g * BPG + blk) * NBUCK + tid;
            uint32 t = bcnt[idx];
            bcnt[idx] = run;          // per-(block,bucket) prefix within bucket
            run += t;
        }
        btot[tid] = run;
    }
    __syncthreads();
    if (tid == 0) {
        uint32 run = 0;
        for (int k = 0; k < NBUCK; ++k) { bbase[g * 158 + k] = run; run += btot[k]; }
        bbase[g * 158 + NBUCK] = run;   // == N_EDGES
    }
}

// ---- bucket phase C: partition edges into bucket-major P (packed) ----
__launch_bounds__(512)
__global__ void bpart_kernel(const int* __restrict__ ea, const int* __restrict__ ep,
                             const int* __restrict__ en, const uint32* __restrict__ bcnt,
                             const uint32* __restrict__ bbase, uint32* __restrict__ P) {
    __shared__ uint32 cur[NBUCK];
    int g = blockIdx.y, blk = blockIdx.x, tid = threadIdx.x;
    const int* e = (g == 0) ? ea : (g == 1) ? ep : en;
    if (tid < NBUCK)
        cur[tid] = bbase[g * 158 + tid] + bcnt[((size_t)g * BPG + blk) * NBUCK + tid];
    __syncthreads();
    int base = blk * CHUNK;
    uint32* Pg = P + (size_t)g * N_EDGES;
    for (int i = tid; i < CHUNK; i += 512) {
        int src = e[base + i];
        int dst = e[N_EDGES + base + i];
        uint32 pos = atomicAdd(&cur[dst >> BSH], 1u);
        Pg[pos] = (uint32)src | ((uint32)(dst & 127) << 16);
    }
}

// ---- bucket phase D fused with L1: per-bucket CSR -> rp/col, plus
//      scalar aggregation + pattern-table MLP1 -> X1 for the bucket's nodes ----
__launch_bounds__(256)
__global__ void bcsr_l1_kernel(const uint32* __restrict__ bbase, const uint32* __restrict__ P,
                               const float* __restrict__ xa, const float* __restrict__ xp,
                               const float* __restrict__ xn,
                               const float* __restrict__ ts, const float* __restrict__ UV,
                               int* __restrict__ rp, int* __restrict__ col,
                               uint32* __restrict__ X1) {
    __shared__ uint32 h[128];
    __shared__ uint32 lscan[128];
    __shared__ float accs[128];
    __shared__ float tsh[128];
    __shared__ int pat[128];
    int k = blockIdx.x, g = blockIdx.y, tid = threadIdx.x;
    const float* x = (g == 0) ? xa : (g == 1) ? xp : xn;
    int beg = (int)bbase[g * 158 + k], end = (int)bbase[g * 158 + k + 1];
    int size = end - beg;
    int n0 = k * 128;
    int cnt_nodes = NB - n0; if (cnt_nodes > 128) cnt_nodes = 128;
    if (tid < 128) { h[tid] = 0; accs[tid] = 0.0f; tsh[tid] = ts[tid]; }
    __syncthreads();
    const uint32* Pg = P + (size_t)g * N_EDGES + beg;
    for (int i = tid; i < size; i += 256)
        atomicAdd(&h[(Pg[i] >> 16) & 127], 1u);
    __syncthreads();
    if (tid == 0) {
        uint32 run = 0;
        for (int d = 0; d < 128; ++d) { lscan[d] = run; run += h[d]; }
    }
    __syncthreads();
    if (tid < cnt_nodes) rp[g * (NB + 1) + n0 + tid] = beg + (int)lscan[tid];
    if (k == NBUCK - 1 && tid == 0) rp[g * (NB + 1) + NB] = end;
    if (tid < 128) h[tid] = lscan[tid];      // repurpose as rank cursors
    __syncthreads();
    int* colg = col + (size_t)g * N_EDGES + beg;
    for (int i = tid; i < size; i += 256) {
        uint32 w = Pg[i];
        int d = (w >> 16) & 127;
        int src = (int)(w & 0xffffu);
        uint32 r = atomicAdd(&h[d], 1u);
        colg[r] = src;                       // scatter within this block's ~15KB window
        atomicAdd(&accs[d], x[src]);         // LDS float accumulation
    }
    __syncthreads();
    if (tid < cnt_nodes) {
        float s = accs[tid] + x[n0 + tid];
        int lo = 0, hi = 128;
        while (lo < hi) { int mid = (lo + hi) >> 1; if (tsh[mid] < s) lo = mid + 1; else hi = mid; }
        pat[tid] = lo;
        accs[tid] = s;
    }
    __syncthreads();
    // write X1 rows: 128 nodes x 64 packed words
    uint32* X1g = X1 + ((size_t)g * NB + n0) * 64;
#pragma unroll 4
    for (int it = 0; it < 32; ++it) {
        int idx = it * 256 + tid;
        int d = idx >> 6, w = idx & 63;
        if (d < cnt_nodes) {
            const float* Up = UV + (size_t)pat[d] * 256;
            float s = accs[d];
            float2 u = *(const float2*)&Up[w * 2];
            float2 v = *(const float2*)&Up[128 + w * 2];
            float r0 = fmaxf(fmaf(s, u.x, v.x), 0.0f);
            float r1 = fmaxf(fmaf(s, u.y, v.y), 0.0f);
            X1g[(size_t)d * 64 + w] = pack2(r0, r1);
        }
    }
}

// ---- L2 aggregation: single launch, 3 phases x 2 tasks x 4 XCDs.
// Masked full-ILP loop: every iter processes 16 edges with 4 loads in flight. ----
__launch_bounds__(256)
__global__ void gather2_kernel(const int* __restrict__ rp, const int* __restrict__ col,
                               const uint32* __restrict__ X1, uint32* __restrict__ H2) {
    int b = blockIdx.x;                        // 0..29999
    int xcd = b & 7, s = b >> 3;               // s 0..3749
    int phase = s / 1250, slot = s - phase * 1250;
    const int gt[3][2] = {{0, 1}, {2, 2}, {0, 1}};
    const int ht[3][2] = {{0, 0}, {0, 1}, {1, 1}};
    int g = gt[phase][xcd >> 2];
    int h = ht[phase][xcd >> 2];
    int nb = slot * 4 + (xcd & 3);             // 0..4999
    int node = nb * 4 + (threadIdx.x >> 6);
    int lane = threadIdx.x & 63;
    int sub = lane >> 4;                       // edge slot 0..3
    int w = lane & 15;                         // uint2 index within 128B half
    const int* rpg = rp + g * (NB + 1);
    const int* clg = col + (size_t)g * N_EDGES;
    int beg = rpg[node], end = rpg[node + 1];
    const uint32* Bg = X1 + (size_t)g * NB * 64 + h * 32;
    float a0 = 0.f, a1 = 0.f, a2 = 0.f, a3 = 0.f;
    int endm1 = end - 1;
    for (int j = beg; j < end; j += 16) {      // 16 edges/iter, 4 loads in flight
        int jb = j + sub * 4;
        int e0 = min(jb, endm1), e1 = min(jb + 1, endm1);
        int e2 = min(jb + 2, endm1), e3 = min(jb + 3, endm1);
        int c0 = clg[e0], c1 = clg[e1], c2 = clg[e2], c3 = clg[e3];
        uint2 v0 = *(const uint2*)&Bg[(size_t)c0 * 64 + w * 2];
        uint2 v1 = *(const uint2*)&Bg[(size_t)c1 * 64 + w * 2];
        uint2 v2 = *(const uint2*)&Bg[(size_t)c2 * 64 + w * 2];
        uint2 v3 = *(const uint2*)&Bg[(size_t)c3 * 64 + w * 2];
        if (jb     >= end) { v0.x = 0u; v0.y = 0u; }
        if (jb + 1 >= end) { v1.x = 0u; v1.y = 0u; }
        if (jb + 2 >= end) { v2.x = 0u; v2.y = 0u; }
        if (jb + 3 >= end) { v3.x = 0u; v3.y = 0u; }
        a0 += bf2f(v0.x & 0xffffu) + bf2f(v1.x & 0xffffu) + bf2f(v2.x & 0xffffu) + bf2f(v3.x & 0xffffu);
        a1 += bf2f(v0.x >> 16)     + bf2f(v1.x >> 16)     + bf2f(v2.x >> 16)     + bf2f(v3.x >> 16);
        a2 += bf2f(v0.y & 0xffffu) + bf2f(v1.y & 0xffffu) + bf2f(v2.y & 0xffffu) + bf2f(v3.y & 0xffffu);
        a3 += bf2f(v0.y >> 16)     + bf2f(v1.y >> 16)     + bf2f(v2.y >> 16)     + bf2f(v3.y >> 16);
    }
    a0 += __shfl_xor(a0, 16); a0 += __shfl_xor(a0, 32);
    a1 += __shfl_xor(a1, 16); a1 += __shfl_xor(a1, 32);
    a2 += __shfl_xor(a2, 16); a2 += __shfl_xor(a2, 32);
    a3 += __shfl_xor(a3, 16); a3 += __shfl_xor(a3, 32);
    if (sub == 0) {
        uint2 sv = *(const uint2*)&Bg[(size_t)node * 64 + w * 2];
        a0 += bf2f(sv.x & 0xffffu); a1 += bf2f(sv.x >> 16);
        a2 += bf2f(sv.y & 0xffffu); a3 += bf2f(sv.y >> 16);
        uint2 o; o.x = pack2(a0, a1); o.y = pack2(a2, a3);
        *(uint2*)&H2[(size_t)(g * NB + node) * 64 + h * 32 + w * 2] = o;
    }
}

// ---- MFMA MLP2: x2 = relu(relu(h2@W21+b21)@W22+b22), pool-only ----
__launch_bounds__(256)
__global__ void mlp2_kernel(const uint32* __restrict__ H2,
                            const uint32* __restrict__ W21p, const float* __restrict__ b21,
                            const uint32* __restrict__ W22p, const float* __restrict__ b22,
                            float* __restrict__ gsum) {
    __shared__ uint32 tl[64 * 64];      // t tile, bf16, XOR-swizzled rows of 256B
    __shared__ float psum[HID];
    int g = blockIdx.y;
    int base = blockIdx.x * 64;
    int nvalid = NB - base; if (nvalid > 64) nvalid = 64;
    int tid = threadIdx.x;
    int wave = tid >> 6, l = tid & 63;
    int lq = l >> 4, lr = l & 15;
    if (tid < HID) psum[tid] = 0.0f;
    __syncthreads();

    f32x4 acc[8];
#pragma unroll
    for (int c = 0; c < 8; ++c) acc[c] = (f32x4){0.f, 0.f, 0.f, 0.f};
    int arow = wave * 16 + lr;
    int arowc = (arow < nvalid) ? arow : 0;
    const uint32* h2row = H2 + ((size_t)g * NB + base + arowc) * 64;
#pragma unroll
    for (int t = 0; t < 4; ++t) {
        uint4 av = *(const uint4*)&h2row[t * 16 + lq * 4];
        bf16x8v af = __builtin_bit_cast(bf16x8v, av);
#pragma unroll
        for (int c = 0; c < 8; ++c) {
            uint4 bv = *(const uint4*)&W21p[((t * 8 + c) * 64 + l) * 4];
            acc[c] = __builtin_amdgcn_mfma_f32_16x16x32_bf16(
                af, __builtin_bit_cast(bf16x8v, bv), acc[c], 0, 0, 0);
        }
    }
    unsigned short* tls = (unsigned short*)tl;
#pragma unroll
    for (int c = 0; c < 8; ++c) {
        int colv = c * 16 + lr;
        float bb = b21[colv];
#pragma unroll
        for (int q = 0; q < 4; ++q) {
            int row = wave * 16 + lq * 4 + q;
            float v = fmaxf(acc[c][q] + bb, 0.0f);
            int byte = row * 256 + ((colv * 2) ^ ((row & 7) << 4));
            tls[byte >> 1] = f2bf(v);
        }
    }
    f32x4 acc2[8];
#pragma unroll
    for (int c = 0; c < 8; ++c) acc2[c] = (f32x4){0.f, 0.f, 0.f, 0.f};
#pragma unroll
    for (int t = 0; t < 4; ++t) {
        int rbyte = arow * 256 + (((t * 64 + lq * 16)) ^ ((arow & 7) << 4));
        uint4 av = *(const uint4*)((const char*)tl + rbyte);
        bf16x8v af = __builtin_bit_cast(bf16x8v, av);
#pragma unroll
        for (int c = 0; c < 8; ++c) {
            uint4 bv = *(const uint4*)&W22p[((t * 8 + c) * 64 + l) * 4];
            acc2[c] = __builtin_amdgcn_mfma_f32_16x16x32_bf16(
                af, __builtin_bit_cast(bf16x8v, bv), acc2[c], 0, 0, 0);
        }
    }
#pragma unroll
    for (int c = 0; c < 8; ++c) {
        float bb = b22[c * 16 + lr];
        float s = 0.0f;
#pragma unroll
        for (int q = 0; q < 4; ++q) {
            int row = wave * 16 + lq * 4 + q;
            float v = fmaxf(acc2[c][q] + bb, 0.0f);
            s += (row < nvalid) ? v : 0.0f;
        }
        s += __shfl_xor(s, 16);
        s += __shfl_xor(s, 32);
        if (lq == 0) atomicAdd(&psum[c * 16 + lr], s);
    }
    __syncthreads();
    if (tid < HID) atomicAdd(&gsum[g * HID + tid], psum[tid]);
}

// ---- triplet head ----
__global__ void final_kernel(const float* __restrict__ gsum, const float* __restrict__ Wf,
                             const float* __restrict__ bf, float* __restrict__ out) {
    int tid = threadIdx.x;  // 384
    int g = tid >> 7;
    int o = tid & 127;
    float acc = bf[o];
    for (int k = 0; k < HID; ++k)
        acc += gsum[g * HID + k] * Wf[k * HID + o];
    out[g * HID + o] = acc;
}

extern "C" void kernel_launch(void* const* d_in, const int* in_sizes, int n_in,
                              void* d_out, int out_size, void* d_ws, size_t ws_size,
                              hipStream_t stream) {
    const float* xa = (const float*)d_in[0];
    const int*   ea = (const int*)d_in[1];
    const float* xp = (const float*)d_in[2];
    const int*   ep = (const int*)d_in[3];
    const float* xn = (const float*)d_in[4];
    const int*   en = (const int*)d_in[5];
    const float* W11 = (const float*)d_in[6];
    const float* b11 = (const float*)d_in[7];
    const float* W12 = (const float*)d_in[8];
    const float* b12 = (const float*)d_in[9];
    const float* W21 = (const float*)d_in[10];
    const float* b21 = (const float*)d_in[11];
    const float* W22 = (const float*)d_in[12];
    const float* b22 = (const float*)d_in[13];
    const float* Wf  = (const float*)d_in[14];
    const float* bf  = (const float*)d_in[15];

    float*  ws    = (float*)d_ws;
    uint32* P     = (uint32*)(ws + P_OFF);
    uint32* bcnt  = (uint32*)(ws + BCNT_OFF);
    uint32* bbase = (uint32*)(ws + BBASE_OFF);
    uint32* X1    = (uint32*)(ws + X1_OFF);
    uint32* H2    = (uint32*)(ws + H2_OFF);
    int*    col   = (int*)(ws + COL_OFF);
    int*    rp    = (int*)(ws + RP_OFF);
    float*  gsum  = ws + GSUM_OFF;
    float*  ts    = ws + TS_OFF;
    float*  UV    = ws + UV_OFF;
    uint32* W21p  = (uint32*)(ws + W21P_OFF);
    uint32* W22p  = (uint32*)(ws + W22P_OFF);
    float*  out   = (float*)d_out;

    prep2_kernel<<<16, 256, 0, stream>>>(W11, b11, W12, b12, W21, W22, ts, UV, W21p, W22p, gsum);
    // bucket-sorted CSR build (LDS atomics only, write-local scatter)
    bhist_kernel<<<dim3(BPG, 3), 512, 0, stream>>>(ea, ep, en, bcnt);
    bscan_kernel<<<3, 256, 0, stream>>>(bcnt, bbase);
    bpart_kernel<<<dim3(BPG, 3), 512, 0, stream>>>(ea, ep, en, bcnt, bbase, P);
    bcsr_l1_kernel<<<dim3(NBUCK, 3), 256, 0, stream>>>(bbase, P, xa, xp, xn, ts, UV, rp, col, X1);
    // L2 aggregation: one launch, phase schedule embedded
    gather2_kernel<<<30000, 256, 0, stream>>>(rp, col, X1, H2);
    mlp2_kernel<<<dim3(NBLK64, 3), 256, 0, stream>>>(H2, W21p, b21, W22p, b22, gsum);
    final_kernel<<<1, 384, 0, stream>>>(gsum, Wf, bf, out);
}